// Round 14
// baseline (994.094 us; speedup 1.0000x reference)
//
#include <hip/hip_runtime.h>
#include <hip/hip_bf16.h>
#include <math.h>

#define N_NODES 20000
#define N_EDGES 400000
#define NH 10

typedef __attribute__((ext_vector_type(8))) short short8v;
typedef __attribute__((ext_vector_type(4))) float f32x4;

// ---------------------------------------------------------------- helpers
__device__ __forceinline__ float gelu_f(float x) {
    float x3 = x * x * x;
    return 0.5f * x * (1.0f + tanhf(0.7978845608028654f * (x + 0.044715f * x3)));
}
__device__ __forceinline__ float elu_f(float x) {
    return x > 0.0f ? x : (expf(x) - 1.0f);
}
__device__ __forceinline__ float bf_lo(unsigned int w) {
    return __uint_as_float(w << 16);
}
__device__ __forceinline__ float bf_hi(unsigned int w) {
    return __uint_as_float(w & 0xffff0000u);
}
__device__ __forceinline__ unsigned short f2b(float x) {   // RNE f32->bf16 bits
    unsigned int u = __float_as_uint(x);
    return (unsigned short)((u + 0x7fffu + ((u >> 16) & 1u)) >> 16);
}

// ---------------------------------------------------------------- paired MFMA GEMM
// Two independent GEMMs in one launch (blockIdx.z selects). Per-z: A bf16 [M][K],
// W transposed bf16 [N][K], bias f32, C = act(A@W+b). BM=BN=128, BK=32, 4 waves,
// register prefetch of next K-tile. K multiple of 32.
struct GemmPair {
    const __hip_bfloat16 *A0, *A1, *W0, *W1;
    const float *b0, *b1;
    void *C0, *C1;
    int N0, N1;
};
template<int ACT, typename OUT>
__global__ __launch_bounds__(256) void gemm2_kernel(GemmPair P, int M, int K)
{
    constexpr int PITCH = 40;
    __shared__ __align__(16) unsigned short As[128 * PITCH];
    __shared__ __align__(16) unsigned short Bs[128 * PITCH];
    const int z = blockIdx.z;
    const __hip_bfloat16* A  = z ? P.A1 : P.A0;
    const __hip_bfloat16* WT = z ? P.W1 : P.W0;
    const float* bias = z ? P.b1 : P.b0;
    OUT* C = (OUT*)(z ? P.C1 : P.C0);
    const int N = z ? P.N1 : P.N0;

    const int tid = threadIdx.x;
    const int m0 = blockIdx.y * 128, n0 = blockIdx.x * 128;
    if (n0 >= N) return;
    const int w = tid >> 6, l = tid & 63;
    const int wr = w >> 1, wc = w & 1;
    const int lr = l & 15, lk = l >> 4;

    const int srow = tid >> 1, sseg = (tid & 1) * 16;
    const bool ainb = (m0 + srow) < M;
    const bool binb = (n0 + srow) < N;
    const __hip_bfloat16* aptr = A + (size_t)(m0 + srow) * K + sseg;
    const __hip_bfloat16* bptr = WT + (size_t)(n0 + srow) * K + sseg;

    int4 ra0, ra1, rb0, rb1;
    auto ld = [&](int k0) {
        ra0 = ainb ? *reinterpret_cast<const int4*>(aptr + k0)     : make_int4(0, 0, 0, 0);
        ra1 = ainb ? *reinterpret_cast<const int4*>(aptr + k0 + 8) : make_int4(0, 0, 0, 0);
        rb0 = binb ? *reinterpret_cast<const int4*>(bptr + k0)     : make_int4(0, 0, 0, 0);
        rb1 = binb ? *reinterpret_cast<const int4*>(bptr + k0 + 8) : make_int4(0, 0, 0, 0);
    };

    f32x4 acc[4][4] = {};
    ld(0);
    for (int k0 = 0; k0 < K; k0 += 32) {
        *reinterpret_cast<int4*>(&As[srow * PITCH + sseg])     = ra0;
        *reinterpret_cast<int4*>(&As[srow * PITCH + sseg + 8]) = ra1;
        *reinterpret_cast<int4*>(&Bs[srow * PITCH + sseg])     = rb0;
        *reinterpret_cast<int4*>(&Bs[srow * PITCH + sseg + 8]) = rb1;
        __syncthreads();
        if (k0 + 32 < K) ld(k0 + 32);
        short8v a[4], b[4];
        #pragma unroll
        for (int mi = 0; mi < 4; ++mi)
            a[mi] = *reinterpret_cast<const short8v*>(
                &As[(wr * 64 + mi * 16 + lr) * PITCH + lk * 8]);
        #pragma unroll
        for (int ni = 0; ni < 4; ++ni)
            b[ni] = *reinterpret_cast<const short8v*>(
                &Bs[(wc * 64 + ni * 16 + lr) * PITCH + lk * 8]);
        #pragma unroll
        for (int mi = 0; mi < 4; ++mi)
            #pragma unroll
            for (int ni = 0; ni < 4; ++ni)
                acc[mi][ni] = __builtin_amdgcn_mfma_f32_16x16x32_bf16(
                    a[mi], b[ni], acc[mi][ni], 0, 0, 0);
        __syncthreads();
    }
    #pragma unroll
    for (int ni = 0; ni < 4; ++ni) {
        const int col = n0 + wc * 64 + ni * 16 + lr;
        if (col >= N) continue;
        const float bv = bias[col];
        #pragma unroll
        for (int mi = 0; mi < 4; ++mi) {
            const int rb = m0 + wr * 64 + mi * 16 + lk * 4;
            #pragma unroll
            for (int j = 0; j < 4; ++j) {
                const int m = rb + j;
                if (m >= M) continue;
                float v = acc[mi][ni][j] + bv;
                if (ACT == 1) v = elu_f(v);
                if constexpr (sizeof(OUT) == 2)
                    C[(size_t)m * N + col] = __float2bfloat16(v);
                else
                    C[(size_t)m * N + col] = v;
            }
        }
    }
}

// ---------------------------------------------------------------- paired weight transpose
// f32 [K][N] -> bf16 [N][K], two tensors per launch (blockIdx.z).
__global__ void transpose2_kernel(const float* in0, const float* in1,
                                  __hip_bfloat16* out0, __hip_bfloat16* out1,
                                  int K0, int N0, int K1, int N1)
{
    __shared__ float tile[32][33];
    const int z = blockIdx.z;
    const float* in = z ? in1 : in0;
    __hip_bfloat16* out = z ? out1 : out0;
    const int K = z ? K1 : K0, N = z ? N1 : N0;
    const int nb = blockIdx.x * 32, kb = blockIdx.y * 32;
    if (nb >= N || kb >= K) return;
    const int tx = threadIdx.x & 31, ty = threadIdx.x >> 5;
    for (int j = ty; j < 32; j += 8) {
        int k = kb + j, n = nb + tx;
        tile[j][tx] = (k < K && n < N) ? in[(size_t)k * N + n] : 0.f;
    }
    __syncthreads();
    for (int j = ty; j < 32; j += 8) {
        int n = nb + j, k = kb + tx;
        if (n < N && k < K) out[(size_t)n * K + k] = __float2bfloat16(tile[tx][j]);
    }
}

// both input tensors f32 -> bf16 in one launch (blockIdx.y selects tensor)
__global__ void convert_in_kernel(const float* __restrict__ in0, const float* __restrict__ in1,
                                  __hip_bfloat16* __restrict__ out0,
                                  __hip_bfloat16* __restrict__ out1, int n4)
{
    int i = blockIdx.x * blockDim.x + threadIdx.x;
    if (i >= n4) return;
    const float* in = blockIdx.y ? in1 : in0;
    __hip_bfloat16* out = blockIdx.y ? out1 : out0;
    float4 v = reinterpret_cast<const float4*>(in)[i];
    ushort4 b;
    b.x = f2b(v.x); b.y = f2b(v.y); b.z = f2b(v.z); b.w = f2b(v.w);
    reinterpret_cast<ushort4*>(out)[i] = b;
}

// per-type q|k|v weight prep, BOTH types in one launch (blockIdx.y = type).
// WT[3HD][fin] bf16 + BIAS[3HD] f32 per type.
__global__ void prep_qkv2_kernel(const float* __restrict__ qw, const float* __restrict__ qb,
                                 const float* __restrict__ kw, const float* __restrict__ kb,
                                 const float* __restrict__ vw, const float* __restrict__ vb,
                                 const float* __restrict__ arel, const float* __restrict__ mrel,
                                 __hip_bfloat16* __restrict__ WT0, float* __restrict__ B0,
                                 __hip_bfloat16* __restrict__ WT1, float* __restrict__ B1,
                                 int fin, int D, int HD)
{
    const int type = blockIdx.y;
    const size_t woff = (size_t)type * fin * HD;
    const size_t roff = (size_t)type * NH * D * D;
    __hip_bfloat16* WT = type ? WT1 : WT0;
    float* BIAS = type ? B1 : B0;
    const int F1 = fin + 1;
    int tid = blockIdx.x * blockDim.x + threadIdx.x;
    if (tid >= 3 * HD * F1) return;
    const int f = tid % F1;
    const int col3 = tid / F1;
    const int sec = col3 / HD;
    const int col = col3 - sec * HD;
    float val;
    if (sec == 0) {
        val = (f < fin) ? qw[woff + (size_t)f * HD + col] : qb[type * HD + col];
    } else {
        const float* W = (sec == 1) ? kw : vw;
        const float* B = (sec == 1) ? kb : vb;
        const float* R = ((sec == 1) ? arel : mrel) + roff;
        const int h = col / D, e = col - h * D;
        const float* src = (f < fin) ? W + woff + (size_t)f * HD + h * D
                                     : B + type * HD + h * D;
        const float* r = R + (size_t)h * D * D + e;
        float acc = 0.f;
        for (int d = 0; d < D; ++d) acc = fmaf(src[d], r[(size_t)d * D], acc);
        val = acc;
    }
    if (f < fin) WT[(size_t)col3 * fin + f] = __float2bfloat16(val);
    else         BIAS[col3] = val;
}

// ---------------------------------------------------------------- fused edge pipeline (both relations)
// Block-per-(rel,dst): grid = 2N, rel = blockIdx&1, dst = blockIdx>>1.
// Node tables T*[N, 3HD] bf16 = (q | kr | vr). NO-MAX softmax (logits tiny; see
// R13). NEW: vr gathers are issued into REGISTERS right after srcs staging so
// they fly concurrently with the kr/logit gathers -- removes one serial
// ~700-cycle gather round from the per-chunk critical path. C=32 bounds the
// per-lane register cost (NMAX=C/G uint4, static-unrolled + predicated).
template<int D>
__global__ __launch_bounds__(256) void edge_fused_kernel(
    const __hip_bfloat16* __restrict__ Ta, const __hip_bfloat16* __restrict__ Tu,
    const int* __restrict__ rp0, const int* __restrict__ src0, const float* __restrict__ eav0,
    const int* __restrict__ rp1, const int* __restrict__ src1, const float* __restrict__ eav1,
    const float* __restrict__ prel, const float* __restrict__ ew,
    const float* __restrict__ eb,                 // [2*NH]
    __hip_bfloat16* __restrict__ outA, __hip_bfloat16* __restrict__ outU,
    float scale)
{
    constexpr int HD = NH * D;
    constexpr int S = 3 * HD;
    constexpr int C = 32;                 // edge chunk; Poisson(20): 1 chunk ~99.5%
    constexpr int POS = HD / 8;           // 16B output chunks (8 bf16)
    constexpr int G = (POS * 8 <= 256) ? 8 : 4;   // D=16: 20x8; D=32: 40x4 = 160 lanes
    constexpr int NMAX = C / G;           // max edges per agg lane per chunk (4 or 8)
    __shared__ float q_s[HD];
    __shared__ float ls[C][NH];
    __shared__ int   srcs[C];
    __shared__ float eas[C];
    __shared__ float prel_s[NH], ew_s[NH], eb_s[NH];

    const int b = blockIdx.x;
    const int rel = b & 1, dst = b >> 1;
    const int t = threadIdx.x;
    const __hip_bfloat16* Tkv = rel ? Tu : Ta;
    const __hip_bfloat16* Tq  = rel ? Ta : Tu;
    const int* rp    = rel ? rp1 : rp0;
    const int* srcA  = rel ? src1 : src0;
    const float* eav = rel ? eav1 : eav0;
    __hip_bfloat16* out = rel ? outA : outU;   // rel0: dst=user -> outU; rel1: dst=ant -> outA

    const int s0 = rp[dst], deg = rp[dst + 1] - s0;

    // stage q row (bf16 -> f32)
    {
        const unsigned int* qrow = (const unsigned int*)(Tq + (size_t)dst * S);
        for (int i = t; i < HD / 2; i += 256) {
            unsigned int wd = qrow[i];
            q_s[2 * i]     = bf_lo(wd);
            q_s[2 * i + 1] = bf_hi(wd);
        }
    }
    if (t < NH) { prel_s[t] = prel[rel * NH + t]; ew_s[t] = ew[rel * NH + t];
                  eb_s[t] = eb[rel * NH + t]; }
    const int apos = t / G, ag = t % G;   // agg role
    const int ah = (apos * 8) / D;        // head of this 16B chunk (8 | D)
    float a8[8] = {};
    float ssum = 0.f;                     // partial softmax denominator for head ah
    __syncthreads();

    for (int base = 0; base < deg; base += C) {
        const int cl = min(C, deg - base);
        if (t < cl) {
            srcs[t] = srcA[s0 + base + t];
            eas[t]  = eav[s0 + base + t];
        }
        __syncthreads();
        // issue vr gathers EARLY into registers (overlap with kr/logit phase)
        uint4 vreg[NMAX];
        if (apos < POS) {
            #pragma unroll
            for (int i = 0; i < NMAX; ++i) {
                const int p = ag + i * G;
                if (p < cl)
                    vreg[i] = ((const uint4*)(Tkv + (size_t)srcs[p] * S + 2 * HD))[apos];
            }
        }
        // exp-logits: item = p*NH + h; kr row read as uint4 (16B)
        for (int item = t; item < cl * NH; item += 256) {
            const int p = item / NH, h = item - p * NH;
            const uint4* kr = (const uint4*)(Tkv + (size_t)srcs[p] * S + HD + h * D);
            const float* qh = q_s + h * D;
            float d0 = 0.f;
            #pragma unroll
            for (int c4 = 0; c4 < D / 8; ++c4) {
                const uint4 wd = kr[c4];
                const float* qq = qh + c4 * 8;
                d0 = fmaf(qq[0], bf_lo(wd.x), d0); d0 = fmaf(qq[1], bf_hi(wd.x), d0);
                d0 = fmaf(qq[2], bf_lo(wd.y), d0); d0 = fmaf(qq[3], bf_hi(wd.y), d0);
                d0 = fmaf(qq[4], bf_lo(wd.z), d0); d0 = fmaf(qq[5], bf_hi(wd.z), d0);
                d0 = fmaf(qq[6], bf_lo(wd.w), d0); d0 = fmaf(qq[7], bf_hi(wd.w), d0);
            }
            ls[p][h] = expf(d0 * scale * prel_s[h] + eas[p] * ew_s[h] + eb_s[h]);
        }
        __syncthreads();
        // weighted accumulation from pre-loaded registers
        if (apos < POS) {
            #pragma unroll
            for (int i = 0; i < NMAX; ++i) {
                const int p = ag + i * G;
                if (p < cl) {
                    const uint4 wd = vreg[i];
                    const float wgt = ls[p][ah];
                    ssum += wgt;
                    a8[0] = fmaf(wgt, bf_lo(wd.x), a8[0]); a8[1] = fmaf(wgt, bf_hi(wd.x), a8[1]);
                    a8[2] = fmaf(wgt, bf_lo(wd.y), a8[2]); a8[3] = fmaf(wgt, bf_hi(wd.y), a8[3]);
                    a8[4] = fmaf(wgt, bf_lo(wd.z), a8[4]); a8[5] = fmaf(wgt, bf_hi(wd.z), a8[5]);
                    a8[6] = fmaf(wgt, bf_lo(wd.w), a8[6]); a8[7] = fmaf(wgt, bf_hi(wd.w), a8[7]);
                }
            }
        }
        __syncthreads();
    }
    // cross-group reduce (G lanes adjacent): a8 and ssum together, then finalize
    if (apos < POS) {
        #pragma unroll
        for (int off = G / 2; off; off >>= 1) {
            #pragma unroll
            for (int j = 0; j < 8; ++j) a8[j] += __shfl_xor(a8[j], off);
            ssum += __shfl_xor(ssum, off);
        }
        if (ag == 0) {
            const float inv = 1.f / (ssum + 1e-16f);
            uint4 o;
            o.x = (unsigned int)f2b(gelu_f(a8[0] * inv)) |
                  ((unsigned int)f2b(gelu_f(a8[1] * inv)) << 16);
            o.y = (unsigned int)f2b(gelu_f(a8[2] * inv)) |
                  ((unsigned int)f2b(gelu_f(a8[3] * inv)) << 16);
            o.z = (unsigned int)f2b(gelu_f(a8[4] * inv)) |
                  ((unsigned int)f2b(gelu_f(a8[5] * inv)) << 16);
            o.w = (unsigned int)f2b(gelu_f(a8[6] * inv)) |
                  ((unsigned int)f2b(gelu_f(a8[7] * inv)) << 16);
            ((uint4*)(out + (size_t)dst * HD))[apos] = o;
        }
    }
}

// ---------------------------------------------------------------- CSR build (both relations batched)
__global__ void count2_kernel(const int* __restrict__ ei0, const int* __restrict__ ei1,
                              int* __restrict__ cnt0, int* __restrict__ cnt1)
{
    int e = blockIdx.x * blockDim.x + threadIdx.x;
    if (e >= N_EDGES) return;
    if (blockIdx.y == 0) atomicAdd(&cnt0[ei0[N_EDGES + e]], 1);
    else                 atomicAdd(&cnt1[ei1[N_EDGES + e]], 1);
}

__global__ void scatter2_kernel(const int* __restrict__ ei0, const float* __restrict__ ea0,
                                const int* __restrict__ ei1, const float* __restrict__ ea1,
                                int* __restrict__ cur0, int* __restrict__ cur1,
                                int* __restrict__ srcA0, float* __restrict__ eaA0,
                                int* __restrict__ srcA1, float* __restrict__ eaA1)
{
    int e = blockIdx.x * blockDim.x + threadIdx.x;
    if (e >= N_EDGES) return;
    const int y = blockIdx.y;
    const int* ei = y ? ei1 : ei0;
    const float* ea = y ? ea1 : ea0;
    int* cursor = y ? cur1 : cur0;
    int* srcA = y ? srcA1 : srcA0;
    float* eaA = y ? eaA1 : eaA0;
    int dst = ei[N_EDGES + e];
    int pos = atomicAdd(&cursor[dst], 1);
    srcA[pos] = ei[e];
    eaA[pos] = ea[e];
}

// both relations in one launch: blockIdx.x = relation
__global__ void exscan2_kernel(const int* __restrict__ cnt0, int* __restrict__ rp0, int* __restrict__ cur0,
                               const int* __restrict__ cnt1, int* __restrict__ rp1, int* __restrict__ cur1,
                               int n)
{
    __shared__ int buf[1024];
    __shared__ int carry;
    const int* cnt = blockIdx.x ? cnt1 : cnt0;
    int* rp = blockIdx.x ? rp1 : rp0;
    int* cursor = blockIdx.x ? cur1 : cur0;
    int t = threadIdx.x;
    if (t == 0) carry = 0;
    __syncthreads();
    for (int base = 0; base < n; base += 1024) {
        int v = (base + t < n) ? cnt[base + t] : 0;
        buf[t] = v;
        __syncthreads();
        for (int off = 1; off < 1024; off <<= 1) {
            int x = (t >= off) ? buf[t - off] : 0;
            __syncthreads();
            buf[t] += x;
            __syncthreads();
        }
        int excl = buf[t] - v + carry;
        if (base + t < n) { rp[base + t] = excl; cursor[base + t] = excl; }
        int total = buf[1023];
        __syncthreads();
        if (t == 0) carry += total;
        __syncthreads();
    }
    if (t == 0) rp[n] = carry;
}

// ---------------------------------------------------------------- batchnorm (both tensors batched)
// STATS layout: [0..N) sum_a, [N..2N) sq_a, [2N..3N) sum_u, [3N..4N) sq_u
__global__ void colstat2_kernel(const __hip_bfloat16* __restrict__ X0,
                                const __hip_bfloat16* __restrict__ X1,
                                float* __restrict__ sums, int M, int N)
{
    __shared__ float ls[256], lq[256];
    const int z = blockIdx.z;
    const __hip_bfloat16* X = z ? X1 : X0;
    float* sm = sums + z * 2 * N;
    int c = blockIdx.x * 64 + (threadIdx.x & 63);
    int rl = threadIdx.x >> 6;
    float s = 0.f, q = 0.f;
    for (int r = blockIdx.y * 4 + rl; r < M; r += gridDim.y * 4) {
        float v = __bfloat162float(X[(size_t)r * N + c]);
        s += v; q = fmaf(v, v, q);
    }
    ls[threadIdx.x] = s; lq[threadIdx.x] = q;
    __syncthreads();
    if (rl == 0) {
        s = ls[threadIdx.x] + ls[threadIdx.x + 64] + ls[threadIdx.x + 128] + ls[threadIdx.x + 192];
        q = lq[threadIdx.x] + lq[threadIdx.x + 64] + lq[threadIdx.x + 128] + lq[threadIdx.x + 192];
        atomicAdd(&sm[c], s);
        atomicAdd(&sm[N + c], q);
    }
}

__global__ void bn2_kernel(__hip_bfloat16* __restrict__ X0, __hip_bfloat16* __restrict__ X1,
                           const float* __restrict__ sums,
                           const float* __restrict__ g, const float* __restrict__ b,
                           int M, int N)
{
    int tid = blockIdx.x * blockDim.x + threadIdx.x;
    if (tid >= 2 * M * N) return;
    const int which = tid >= M * N;
    const int idx = tid - which * M * N;
    const int c = idx % N;
    __hip_bfloat16* X = which ? X1 : X0;
    const float* sm = sums + which * 2 * N;
    float mu = sm[c] / (float)M;
    float var = sm[N + c] / (float)M - mu * mu;
    float x = __bfloat162float(X[idx]);
    X[idx] = __float2bfloat16((x - mu) * rsqrtf(var + 1e-5f) * g[which * N + c]
                              + b[which * N + c]);
}

// ---------------------------------------------------------------- combined output epilogue
// blockIdx.y==0: rownorm on XA -> out[0..N*128); ==1: rowsoftmax on XU -> out[N*128..)
__global__ void epilogue_kernel(const float* __restrict__ XA, const float* __restrict__ XU,
                                float* __restrict__ out)
{
    const int row = blockIdx.x;
    const int l = threadIdx.x;   // 64
    if (blockIdx.y == 0) {
        const float* x = XA + (size_t)row * 128;
        float v0 = x[l], v1 = x[l + 64];
        float ss = v0 * v0 + v1 * v1;
        #pragma unroll
        for (int off = 32; off; off >>= 1) ss += __shfl_xor(ss, off);
        float inv = rsqrtf(ss + 1e-12f);
        out[(size_t)row * 128 + l] = v0 * inv;
        out[(size_t)row * 128 + l + 64] = v1 * inv;
    } else {
        const float* x = XU + (size_t)row * 129;
        float* o = out + (size_t)N_NODES * 128;
        float v0 = x[l], v1 = x[l + 64];
        float v2 = (l == 0) ? x[128] : -3.4e38f;
        float m = fmaxf(fmaxf(v0, v1), v2);
        #pragma unroll
        for (int off = 32; off; off >>= 1) m = fmaxf(m, __shfl_xor(m, off));
        float e0 = expf(v0 - m), e1 = expf(v1 - m);
        float e2 = (l == 0) ? expf(v2 - m) : 0.f;
        float s = e0 + e1 + e2;
        #pragma unroll
        for (int off = 32; off; off >>= 1) s += __shfl_xor(s, off);
        float inv = 1.f / s;
        o[(size_t)row * 129 + l] = e0 * inv;
        o[(size_t)row * 129 + l + 64] = e1 * inv;
        if (l == 0) o[(size_t)row * 129 + 128] = e2 * inv;
    }
}

// ---------------------------------------------------------------- host-side plumbing
template<int ACT, typename OUT>
static inline void launch_gemm2(const __hip_bfloat16* A0, const __hip_bfloat16* W0,
                                const float* b0, OUT* C0, int N0,
                                const __hip_bfloat16* A1, const __hip_bfloat16* W1,
                                const float* b1, OUT* C1, int N1,
                                int M, int K, hipStream_t s)
{
    GemmPair P = { A0, A1, W0, W1, b0, b1, (void*)C0, (void*)C1, N0, N1 };
    const int maxN = N0 > N1 ? N0 : N1;
    dim3 grid((maxN + 127) / 128, (M + 127) / 128, 2);
    gemm2_kernel<ACT, OUT><<<grid, 256, 0, s>>>(P, M, K);
}
static inline void launch_transpose2(const float* in0, const float* in1,
                                     __hip_bfloat16* out0, __hip_bfloat16* out1,
                                     int K0, int N0, int K1, int N1, hipStream_t s)
{
    const int maxN = N0 > N1 ? N0 : N1, maxK = K0 > K1 ? K0 : K1;
    dim3 grid((maxN + 31) / 32, (maxK + 31) / 32, 2);
    transpose2_kernel<<<grid, 256, 0, s>>>(in0, in1, out0, out1, K0, N0, K1, N1);
}

struct LayerParams {
    const float *kw, *kb, *qw, *qb, *vw, *vb, *arel, *mrel, *prel, *ew, *eb, *alw, *alb;
};

struct CsrRel { const int* rp; const int* src; const float* eav; };

template<int D>
static void run_layer(const LayerParams& P, int fin,
                      const __hip_bfloat16* xa, const __hip_bfloat16* xu,
                      __hip_bfloat16* TA, __hip_bfloat16* TU,
                      __hip_bfloat16* AGA, __hip_bfloat16* AGU,
                      __hip_bfloat16* ya, __hip_bfloat16* yu,
                      __hip_bfloat16* WT1, __hip_bfloat16* WT2,
                      float* BIAS1, float* BIAS2,
                      const CsrRel& au, const CsrRel& ua, hipStream_t s)
{
    const int HD = NH * D;
    const float scale = 1.0f / sqrtf((float)D);
    const int gP = (3 * HD * (fin + 1) + 255) / 256;

    // q|k|v weight prep for both types (one launch) + paired table GEMM
    {
        dim3 g(gP, 2);
        prep_qkv2_kernel<<<g, 256, 0, s>>>(P.qw, P.qb, P.kw, P.kb, P.vw, P.vb,
                                           P.arel, P.mrel, WT1, BIAS1, WT2, BIAS2,
                                           fin, D, HD);
    }
    launch_gemm2<0, __hip_bfloat16>(xa, WT1, BIAS1, TA, 3 * HD,
                                    xu, WT2, BIAS2, TU, 3 * HD, N_NODES, fin, s);

    // out = rel ? outA : outU  =>  pass (outA=AGA, outU=AGU); rel0 (dst=user) -> AGU
    edge_fused_kernel<D><<<2 * N_NODES, 256, 0, s>>>(
        TA, TU, au.rp, au.src, au.eav, ua.rp, ua.src, ua.eav,
        P.prel, P.ew, P.eb, AGA, AGU, scale);

    // paired attn-linear (gelu applied in edge kernel), elu-out
    launch_transpose2(P.alw, P.alw + (size_t)HD * HD, WT1, WT2, HD, HD, HD, HD, s);
    launch_gemm2<1, __hip_bfloat16>(AGA, WT1, P.alb, ya, HD,
                                    AGU, WT2, P.alb + HD, yu, HD, N_NODES, HD, s);
}

extern "C" void kernel_launch(void* const* d_in, const int* in_sizes, int n_in,
                              void* d_out, int out_size, void* d_ws, size_t ws_size,
                              hipStream_t stream)
{
    // ---- inputs
    const float* x_ant  = (const float*)d_in[0];
    const float* x_user = (const float*)d_in[1];
    const float* ea_au  = (const float*)d_in[2];
    const float* ea_ua  = (const float*)d_in[3];
    LayerParams L1 = {
        (const float*)d_in[4],  (const float*)d_in[5],  (const float*)d_in[6],
        (const float*)d_in[7],  (const float*)d_in[8],  (const float*)d_in[9],
        (const float*)d_in[10], (const float*)d_in[11], (const float*)d_in[12],
        (const float*)d_in[13], (const float*)d_in[14], (const float*)d_in[15],
        (const float*)d_in[16]
    };
    LayerParams L2 = {
        (const float*)d_in[17], (const float*)d_in[18], (const float*)d_in[19],
        (const float*)d_in[20], (const float*)d_in[21], (const float*)d_in[22],
        (const float*)d_in[23], (const float*)d_in[24], (const float*)d_in[25],
        (const float*)d_in[26], (const float*)d_in[27], (const float*)d_in[28],
        (const float*)d_in[29]
    };
    const float* lin1_w  = (const float*)d_in[30];
    const float* lin1_b  = (const float*)d_in[31];
    const float* bn_g    = (const float*)d_in[32];
    const float* bn_b    = (const float*)d_in[33];
    const float* lin2_wa = (const float*)d_in[34];
    const float* lin2_ba = (const float*)d_in[35];
    const float* lin2_wu = (const float*)d_in[36];
    const float* lin2_bu = (const float*)d_in[37];
    const int*   ei_au   = (const int*)d_in[38];
    const int*   ei_ua   = (const int*)d_in[39];

    // ---- workspace arena (byte carve, 256B aligned)
    char* P8 = (char*)d_ws;
    auto carve = [&](size_t bytes) { char* p = P8; P8 += (bytes + 255) & ~(size_t)255; return p; };
    __hip_bfloat16* XA  = (__hip_bfloat16*)carve((size_t)N_NODES * 128 * 2);
    __hip_bfloat16* XU  = (__hip_bfloat16*)carve((size_t)N_NODES * 128 * 2);
    __hip_bfloat16* TA  = (__hip_bfloat16*)carve((size_t)N_NODES * 960 * 2);
    __hip_bfloat16* TU  = (__hip_bfloat16*)carve((size_t)N_NODES * 960 * 2);
    __hip_bfloat16* AGA = (__hip_bfloat16*)carve((size_t)N_NODES * 320 * 2);
    __hip_bfloat16* AGU = (__hip_bfloat16*)carve((size_t)N_NODES * 320 * 2);
    __hip_bfloat16* YA  = (__hip_bfloat16*)carve((size_t)N_NODES * 320 * 2);
    __hip_bfloat16* YU  = (__hip_bfloat16*)carve((size_t)N_NODES * 320 * 2);
    __hip_bfloat16* L1A = (__hip_bfloat16*)carve((size_t)N_NODES * 512 * 2);
    __hip_bfloat16* L1U = (__hip_bfloat16*)carve((size_t)N_NODES * 512 * 2);
    __hip_bfloat16* WT1 = (__hip_bfloat16*)carve(960 * 320 * 2);
    __hip_bfloat16* WT2 = (__hip_bfloat16*)carve(960 * 320 * 2);
    float* BIAS1 = (float*)carve(960 * 4);
    float* BIAS2 = (float*)carve(960 * 4);
    float* STATS = (float*)carve(2048 * 4);
    int*   rp_au  = (int*)carve((N_NODES + 1) * 4);
    int*   rp_ua  = (int*)carve((N_NODES + 1) * 4);
    int*   src_au = (int*)carve((size_t)N_EDGES * 4);
    float* eav_au = (float*)carve((size_t)N_EDGES * 4);
    int*   src_ua = (int*)carve((size_t)N_EDGES * 4);
    float* eav_ua = (float*)carve((size_t)N_EDGES * 4);
    int*   cursor = (int*)carve((size_t)2 * N_NODES * 4);   // [0..N) au, [N..2N) ua
    int*   counts = (int*)carve((size_t)2 * N_NODES * 4);

    const int gE = (N_EDGES + 255) / 256;

    // ---- CSR build (both relations, batched launches)
    hipMemsetAsync(counts, 0, 2 * N_NODES * sizeof(int), stream);
    {
        dim3 g(gE, 2);
        count2_kernel<<<g, 256, 0, stream>>>(ei_au, ei_ua, counts, counts + N_NODES);
    }
    exscan2_kernel<<<2, 1024, 0, stream>>>(counts, rp_au, cursor,
                                           counts + N_NODES, rp_ua, cursor + N_NODES,
                                           N_NODES);
    {
        dim3 g(gE, 2);
        scatter2_kernel<<<g, 256, 0, stream>>>(ei_au, ea_au, ei_ua, ea_ua,
                                               cursor, cursor + N_NODES,
                                               src_au, eav_au, src_ua, eav_ua);
    }
    CsrRel au = { rp_au, src_au, eav_au };
    CsrRel ua = { rp_ua, src_ua, eav_ua };

    // ---- inputs f32 -> bf16 (one launch)
    {
        dim3 g((N_NODES * 128 / 4 + 255) / 256, 2);
        convert_in_kernel<<<g, 256, 0, stream>>>(x_ant, x_user, XA, XU, N_NODES * 128 / 4);
    }

    // ---- HGT layer 1: fin=128, D=16 -> YA/YU [N,160] bf16 (elu applied)
    run_layer<16>(L1, 128, XA, XU, TA, TU, AGA, AGU, YA, YU,
                  WT1, WT2, BIAS1, BIAS2, au, ua, stream);

    // ---- HGT layer 2: fin=160, D=32 -> outputs into TA/TU (table space dead after edge)
    run_layer<32>(L2, 160, YA, YU, TA, TU, AGA, AGU, TA, TU,
                  WT1, WT2, BIAS1, BIAS2, au, ua, stream);

    // ---- lin1 + elu: [N,320] @ [320,512] -> bf16 (paired)
    launch_transpose2(lin1_w, lin1_w + (size_t)320 * 512, WT1, WT2, 320, 512, 320, 512, stream);
    launch_gemm2<1, __hip_bfloat16>(TA, WT1, lin1_b, L1A, 512,
                                    TU, WT2, lin1_b + 512, L1U, 512, N_NODES, 320, stream);

    // ---- batchnorm (population stats), in-place on bf16 (batched)
    hipMemsetAsync(STATS, 0, 2048 * sizeof(float), stream);
    {
        dim3 g(8, 32, 2);
        colstat2_kernel<<<g, 256, 0, stream>>>(L1A, L1U, STATS, N_NODES, 512);
    }
    bn2_kernel<<<(2 * N_NODES * 512 + 255) / 256, 256, 0, stream>>>(
        L1A, L1U, STATS, bn_g, bn_b, N_NODES, 512);

    // ---- lin2 (f32 out, paired) + combined epilogue; OUT buffers reuse AGA/AGU
    float* OUTA = (float*)AGA;   // [N,128] f32
    float* OUTU = (float*)AGU;   // [N,129] f32
    launch_transpose2(lin2_wa, lin2_wu, WT1, WT2, 512, 128, 512, 129, stream);
    launch_gemm2<0, float>(L1A, WT1, lin2_ba, OUTA, 128,
                           L1U, WT2, lin2_bu, OUTU, 129, N_NODES, 512, stream);
    {
        dim3 g(N_NODES, 2);
        epilogue_kernel<<<g, 64, 0, stream>>>(OUTA, OUTU, (float*)d_out);
    }
}

// Round 15
// 913.428 us; speedup vs baseline: 1.0883x; 1.0883x over previous
//
#include <hip/hip_runtime.h>
#include <hip/hip_bf16.h>
#include <math.h>

#define N_NODES 20000
#define N_EDGES 400000
#define NH 10

typedef __attribute__((ext_vector_type(8))) short short8v;
typedef __attribute__((ext_vector_type(4))) float f32x4;

// ---------------------------------------------------------------- helpers
__device__ __forceinline__ float gelu_f(float x) {
    float x3 = x * x * x;
    return 0.5f * x * (1.0f + tanhf(0.7978845608028654f * (x + 0.044715f * x3)));
}
__device__ __forceinline__ float elu_f(float x) {
    return x > 0.0f ? x : (expf(x) - 1.0f);
}
__device__ __forceinline__ float bf_lo(unsigned int w) {
    return __uint_as_float(w << 16);
}
__device__ __forceinline__ float bf_hi(unsigned int w) {
    return __uint_as_float(w & 0xffff0000u);
}
__device__ __forceinline__ unsigned short f2b(float x) {   // RNE f32->bf16 bits
    unsigned int u = __float_as_uint(x);
    return (unsigned short)((u + 0x7fffu + ((u >> 16) & 1u)) >> 16);
}

// ---------------------------------------------------------------- paired MFMA GEMM
// Two independent GEMMs in one launch (blockIdx.z selects). Per-z: A bf16 [M][K],
// W transposed bf16 [N][K], bias f32, C = act(A@W+b). BM=BN=128, BK=32, 4 waves,
// register prefetch of next K-tile. K multiple of 32.
struct GemmPair {
    const __hip_bfloat16 *A0, *A1, *W0, *W1;
    const float *b0, *b1;
    void *C0, *C1;
    int N0, N1;
};
template<int ACT, typename OUT>
__global__ __launch_bounds__(256) void gemm2_kernel(GemmPair P, int M, int K)
{
    constexpr int PITCH = 40;
    __shared__ __align__(16) unsigned short As[128 * PITCH];
    __shared__ __align__(16) unsigned short Bs[128 * PITCH];
    const int z = blockIdx.z;
    const __hip_bfloat16* A  = z ? P.A1 : P.A0;
    const __hip_bfloat16* WT = z ? P.W1 : P.W0;
    const float* bias = z ? P.b1 : P.b0;
    OUT* C = (OUT*)(z ? P.C1 : P.C0);
    const int N = z ? P.N1 : P.N0;

    const int tid = threadIdx.x;
    const int m0 = blockIdx.y * 128, n0 = blockIdx.x * 128;
    if (n0 >= N) return;
    const int w = tid >> 6, l = tid & 63;
    const int wr = w >> 1, wc = w & 1;
    const int lr = l & 15, lk = l >> 4;

    const int srow = tid >> 1, sseg = (tid & 1) * 16;
    const bool ainb = (m0 + srow) < M;
    const bool binb = (n0 + srow) < N;
    const __hip_bfloat16* aptr = A + (size_t)(m0 + srow) * K + sseg;
    const __hip_bfloat16* bptr = WT + (size_t)(n0 + srow) * K + sseg;

    int4 ra0, ra1, rb0, rb1;
    auto ld = [&](int k0) {
        ra0 = ainb ? *reinterpret_cast<const int4*>(aptr + k0)     : make_int4(0, 0, 0, 0);
        ra1 = ainb ? *reinterpret_cast<const int4*>(aptr + k0 + 8) : make_int4(0, 0, 0, 0);
        rb0 = binb ? *reinterpret_cast<const int4*>(bptr + k0)     : make_int4(0, 0, 0, 0);
        rb1 = binb ? *reinterpret_cast<const int4*>(bptr + k0 + 8) : make_int4(0, 0, 0, 0);
    };

    f32x4 acc[4][4] = {};
    ld(0);
    for (int k0 = 0; k0 < K; k0 += 32) {
        *reinterpret_cast<int4*>(&As[srow * PITCH + sseg])     = ra0;
        *reinterpret_cast<int4*>(&As[srow * PITCH + sseg + 8]) = ra1;
        *reinterpret_cast<int4*>(&Bs[srow * PITCH + sseg])     = rb0;
        *reinterpret_cast<int4*>(&Bs[srow * PITCH + sseg + 8]) = rb1;
        __syncthreads();
        if (k0 + 32 < K) ld(k0 + 32);
        short8v a[4], b[4];
        #pragma unroll
        for (int mi = 0; mi < 4; ++mi)
            a[mi] = *reinterpret_cast<const short8v*>(
                &As[(wr * 64 + mi * 16 + lr) * PITCH + lk * 8]);
        #pragma unroll
        for (int ni = 0; ni < 4; ++ni)
            b[ni] = *reinterpret_cast<const short8v*>(
                &Bs[(wc * 64 + ni * 16 + lr) * PITCH + lk * 8]);
        #pragma unroll
        for (int mi = 0; mi < 4; ++mi)
            #pragma unroll
            for (int ni = 0; ni < 4; ++ni)
                acc[mi][ni] = __builtin_amdgcn_mfma_f32_16x16x32_bf16(
                    a[mi], b[ni], acc[mi][ni], 0, 0, 0);
        __syncthreads();
    }
    #pragma unroll
    for (int ni = 0; ni < 4; ++ni) {
        const int col = n0 + wc * 64 + ni * 16 + lr;
        if (col >= N) continue;
        const float bv = bias[col];
        #pragma unroll
        for (int mi = 0; mi < 4; ++mi) {
            const int rb = m0 + wr * 64 + mi * 16 + lk * 4;
            #pragma unroll
            for (int j = 0; j < 4; ++j) {
                const int m = rb + j;
                if (m >= M) continue;
                float v = acc[mi][ni][j] + bv;
                if (ACT == 1) v = elu_f(v);
                if constexpr (sizeof(OUT) == 2)
                    C[(size_t)m * N + col] = __float2bfloat16(v);
                else
                    C[(size_t)m * N + col] = v;
            }
        }
    }
}

// ---------------------------------------------------------------- batched weight transpose (8 jobs)
// f32 [K][N] -> bf16 [N][K]; blockIdx.z selects job.
struct TJob { const float* in; __hip_bfloat16* out; int K; int N; };
struct TJobs8 { TJob j[8]; };
__global__ void transpose8_kernel(TJobs8 J)
{
    __shared__ float tile[32][33];
    const TJob job = J.j[blockIdx.z];
    const int K = job.K, N = job.N;
    const int nb = blockIdx.x * 32, kb = blockIdx.y * 32;
    if (nb >= N || kb >= K) return;
    const int tx = threadIdx.x & 31, ty = threadIdx.x >> 5;
    for (int j = ty; j < 32; j += 8) {
        int k = kb + j, n = nb + tx;
        tile[j][tx] = (k < K && n < N) ? job.in[(size_t)k * N + n] : 0.f;
    }
    __syncthreads();
    for (int j = ty; j < 32; j += 8) {
        int n = nb + j, k = kb + tx;
        if (n < N && k < K) job.out[(size_t)n * K + k] = __float2bfloat16(tile[tx][j]);
    }
}

// both input tensors f32 -> bf16 in one launch (blockIdx.y selects tensor)
__global__ void convert_in_kernel(const float* __restrict__ in0, const float* __restrict__ in1,
                                  __hip_bfloat16* __restrict__ out0,
                                  __hip_bfloat16* __restrict__ out1, int n4)
{
    int i = blockIdx.x * blockDim.x + threadIdx.x;
    if (i >= n4) return;
    const float* in = blockIdx.y ? in1 : in0;
    __hip_bfloat16* out = blockIdx.y ? out1 : out0;
    float4 v = reinterpret_cast<const float4*>(in)[i];
    ushort4 b;
    b.x = f2b(v.x); b.y = f2b(v.y); b.z = f2b(v.z); b.w = f2b(v.w);
    reinterpret_cast<ushort4*>(out)[i] = b;
}

// q|k|v weight prep for BOTH layers x BOTH types in one launch.
// blockIdx.y = 0..3: layer = y>>1 (0:L1 D=16 fin=128, 1:L2 D=32 fin=160), type = y&1.
// Output per (layer,type): WT[3HD][fin] bf16 + BIAS[3HD] f32.
struct PrepArgs {
    const float *qw1, *qb1, *kw1, *kb1, *vw1, *vb1, *ar1, *mr1;   // layer1
    const float *qw2, *qb2, *kw2, *kb2, *vw2, *vb2, *ar2, *mr2;   // layer2
    __hip_bfloat16 *W1a, *W1u, *W2a, *W2u;
    float *B1a, *B1u, *B2a, *B2u;
};
__global__ void prep_qkv4_kernel(PrepArgs A)
{
    const int y = blockIdx.y;
    const int layer = y >> 1, type = y & 1;
    const int D = layer ? 32 : 16;
    const int fin = layer ? 160 : 128;
    const int HD = NH * D;
    const float* qw = layer ? A.qw2 : A.qw1;
    const float* qb = layer ? A.qb2 : A.qb1;
    const float* kw = layer ? A.kw2 : A.kw1;
    const float* kb = layer ? A.kb2 : A.kb1;
    const float* vw = layer ? A.vw2 : A.vw1;
    const float* vb = layer ? A.vb2 : A.vb1;
    const float* ar = layer ? A.ar2 : A.ar1;
    const float* mr = layer ? A.mr2 : A.mr1;
    __hip_bfloat16* WT = layer ? (type ? A.W2u : A.W2a) : (type ? A.W1u : A.W1a);
    float* BIAS = layer ? (type ? A.B2u : A.B2a) : (type ? A.B1u : A.B1a);
    const size_t woff = (size_t)type * fin * HD;
    const size_t roff = (size_t)type * NH * D * D;

    const int F1 = fin + 1;
    int tid = blockIdx.x * blockDim.x + threadIdx.x;
    if (tid >= 3 * HD * F1) return;
    const int f = tid % F1;
    const int col3 = tid / F1;
    const int sec = col3 / HD;
    const int col = col3 - sec * HD;
    float val;
    if (sec == 0) {
        val = (f < fin) ? qw[woff + (size_t)f * HD + col] : qb[type * HD + col];
    } else {
        const float* W = (sec == 1) ? kw : vw;
        const float* B = (sec == 1) ? kb : vb;
        const float* R = ((sec == 1) ? ar : mr) + roff;
        const int h = col / D, e = col - h * D;
        const float* src = (f < fin) ? W + woff + (size_t)f * HD + h * D
                                     : B + type * HD + h * D;
        const float* r = R + (size_t)h * D * D + e;
        float acc = 0.f;
        for (int d = 0; d < D; ++d) acc = fmaf(src[d], r[(size_t)d * D], acc);
        val = acc;
    }
    if (f < fin) WT[(size_t)col3 * fin + f] = __float2bfloat16(val);
    else         BIAS[col3] = val;
}

// ---------------------------------------------------------------- fused edge pipeline (both relations)
// Block-per-(rel,dst): grid = 2N, rel = blockIdx&1, dst = blockIdx>>1.
// Node tables T*[N, 3HD] bf16 = (q | kr | vr). NO-MAX softmax (logits tiny):
// exp(l)/sum == reference exp(l-m)/sum up to fp rounding; denominator folded
// into the aggregation pass (ssum reduced by the same cross-group shfl).
// R13 design -- measured best (235us); R14's register prefetch dropped
// occupancy 41->31% and regressed, reverted.
template<int D>
__global__ __launch_bounds__(256) void edge_fused_kernel(
    const __hip_bfloat16* __restrict__ Ta, const __hip_bfloat16* __restrict__ Tu,
    const int* __restrict__ rp0, const int* __restrict__ src0, const float* __restrict__ eav0,
    const int* __restrict__ rp1, const int* __restrict__ src1, const float* __restrict__ eav1,
    const float* __restrict__ prel, const float* __restrict__ ew,
    const float* __restrict__ eb,                 // [2*NH]
    __hip_bfloat16* __restrict__ outA, __hip_bfloat16* __restrict__ outU,
    float scale)
{
    constexpr int HD = NH * D;
    constexpr int S = 3 * HD;
    constexpr int C = 64;                 // edge chunk; Poisson(20) max ~50
    constexpr int POS = HD / 8;           // 16B output chunks (8 bf16)
    constexpr int G = (POS * 8 <= 256) ? 8 : 4;   // D=16: 20x8; D=32: 40x4 = 160 lanes
    __shared__ float q_s[HD];
    __shared__ float ls[C][NH];
    __shared__ int   srcs[C];
    __shared__ float eas[C];
    __shared__ float prel_s[NH], ew_s[NH], eb_s[NH];

    const int b = blockIdx.x;
    const int rel = b & 1, dst = b >> 1;
    const int t = threadIdx.x;
    const __hip_bfloat16* Tkv = rel ? Tu : Ta;
    const __hip_bfloat16* Tq  = rel ? Ta : Tu;
    const int* rp    = rel ? rp1 : rp0;
    const int* srcA  = rel ? src1 : src0;
    const float* eav = rel ? eav1 : eav0;
    __hip_bfloat16* out = rel ? outA : outU;   // rel0: dst=user -> outU; rel1: dst=ant -> outA

    const int s0 = rp[dst], deg = rp[dst + 1] - s0;

    // stage q row (bf16 -> f32)
    {
        const unsigned int* qrow = (const unsigned int*)(Tq + (size_t)dst * S);
        for (int i = t; i < HD / 2; i += 256) {
            unsigned int wd = qrow[i];
            q_s[2 * i]     = bf_lo(wd);
            q_s[2 * i + 1] = bf_hi(wd);
        }
    }
    if (t < NH) { prel_s[t] = prel[rel * NH + t]; ew_s[t] = ew[rel * NH + t];
                  eb_s[t] = eb[rel * NH + t]; }
    const int apos = t / G, ag = t % G;   // agg role
    const int ah = (apos * 8) / D;        // head of this 16B chunk (8 | D)
    float a8[8] = {};
    float ssum = 0.f;                     // partial softmax denominator for head ah
    __syncthreads();

    for (int base = 0; base < deg; base += C) {
        const int cl = min(C, deg - base);
        if (t < cl) {
            srcs[t] = srcA[s0 + base + t];
            eas[t]  = eav[s0 + base + t];
        }
        __syncthreads();
        // exp-logits: item = p*NH + h; kr row read as uint4 (16B)
        for (int item = t; item < cl * NH; item += 256) {
            const int p = item / NH, h = item - p * NH;
            const uint4* kr = (const uint4*)(Tkv + (size_t)srcs[p] * S + HD + h * D);
            const float* qh = q_s + h * D;
            float d0 = 0.f;
            #pragma unroll
            for (int c4 = 0; c4 < D / 8; ++c4) {
                const uint4 wd = kr[c4];
                const float* qq = qh + c4 * 8;
                d0 = fmaf(qq[0], bf_lo(wd.x), d0); d0 = fmaf(qq[1], bf_hi(wd.x), d0);
                d0 = fmaf(qq[2], bf_lo(wd.y), d0); d0 = fmaf(qq[3], bf_hi(wd.y), d0);
                d0 = fmaf(qq[4], bf_lo(wd.z), d0); d0 = fmaf(qq[5], bf_hi(wd.z), d0);
                d0 = fmaf(qq[6], bf_lo(wd.w), d0); d0 = fmaf(qq[7], bf_hi(wd.w), d0);
            }
            ls[p][h] = expf(d0 * scale * prel_s[h] + eas[p] * ew_s[h] + eb_s[h]);
        }
        __syncthreads();
        // aggregate: each active lane owns one 16B vr chunk for edges p = ag::G;
        // ssum accumulates this lane's share of the softmax denominator.
        if (apos < POS) {
            for (int p = ag; p < cl; p += G) {
                const uint4* vr = (const uint4*)(Tkv + (size_t)srcs[p] * S + 2 * HD);
                const uint4 wd = vr[apos];
                const float wgt = ls[p][ah];
                ssum += wgt;
                a8[0] = fmaf(wgt, bf_lo(wd.x), a8[0]); a8[1] = fmaf(wgt, bf_hi(wd.x), a8[1]);
                a8[2] = fmaf(wgt, bf_lo(wd.y), a8[2]); a8[3] = fmaf(wgt, bf_hi(wd.y), a8[3]);
                a8[4] = fmaf(wgt, bf_lo(wd.z), a8[4]); a8[5] = fmaf(wgt, bf_hi(wd.z), a8[5]);
                a8[6] = fmaf(wgt, bf_lo(wd.w), a8[6]); a8[7] = fmaf(wgt, bf_hi(wd.w), a8[7]);
            }
        }
        __syncthreads();
    }
    // cross-group reduce (G lanes adjacent): a8 and ssum together, then finalize
    if (apos < POS) {
        #pragma unroll
        for (int off = G / 2; off; off >>= 1) {
            #pragma unroll
            for (int j = 0; j < 8; ++j) a8[j] += __shfl_xor(a8[j], off);
            ssum += __shfl_xor(ssum, off);
        }
        if (ag == 0) {
            const float inv = 1.f / (ssum + 1e-16f);
            uint4 o;
            o.x = (unsigned int)f2b(gelu_f(a8[0] * inv)) |
                  ((unsigned int)f2b(gelu_f(a8[1] * inv)) << 16);
            o.y = (unsigned int)f2b(gelu_f(a8[2] * inv)) |
                  ((unsigned int)f2b(gelu_f(a8[3] * inv)) << 16);
            o.z = (unsigned int)f2b(gelu_f(a8[4] * inv)) |
                  ((unsigned int)f2b(gelu_f(a8[5] * inv)) << 16);
            o.w = (unsigned int)f2b(gelu_f(a8[6] * inv)) |
                  ((unsigned int)f2b(gelu_f(a8[7] * inv)) << 16);
            ((uint4*)(out + (size_t)dst * HD))[apos] = o;
        }
    }
}

// ---------------------------------------------------------------- CSR build (both relations batched)
__global__ void count2_kernel(const int* __restrict__ ei0, const int* __restrict__ ei1,
                              int* __restrict__ cnt0, int* __restrict__ cnt1)
{
    int e = blockIdx.x * blockDim.x + threadIdx.x;
    if (e >= N_EDGES) return;
    if (blockIdx.y == 0) atomicAdd(&cnt0[ei0[N_EDGES + e]], 1);
    else                 atomicAdd(&cnt1[ei1[N_EDGES + e]], 1);
}

__global__ void scatter2_kernel(const int* __restrict__ ei0, const float* __restrict__ ea0,
                                const int* __restrict__ ei1, const float* __restrict__ ea1,
                                int* __restrict__ cur0, int* __restrict__ cur1,
                                int* __restrict__ srcA0, float* __restrict__ eaA0,
                                int* __restrict__ srcA1, float* __restrict__ eaA1)
{
    int e = blockIdx.x * blockDim.x + threadIdx.x;
    if (e >= N_EDGES) return;
    const int y = blockIdx.y;
    const int* ei = y ? ei1 : ei0;
    const float* ea = y ? ea1 : ea0;
    int* cursor = y ? cur1 : cur0;
    int* srcA = y ? srcA1 : srcA0;
    float* eaA = y ? eaA1 : eaA0;
    int dst = ei[N_EDGES + e];
    int pos = atomicAdd(&cursor[dst], 1);
    srcA[pos] = ei[e];
    eaA[pos] = ea[e];
}

// both relations in one launch: blockIdx.x = relation.
// Each thread owns CH contiguous elements (serial sum) + one 1024-wide scan.
__global__ void exscan2_kernel(const int* __restrict__ cnt0, int* __restrict__ rp0, int* __restrict__ cur0,
                               const int* __restrict__ cnt1, int* __restrict__ rp1, int* __restrict__ cur1,
                               int n)
{
    __shared__ int sums[1024];
    const int* cnt = blockIdx.x ? cnt1 : cnt0;
    int* rp = blockIdx.x ? rp1 : rp0;
    int* cursor = blockIdx.x ? cur1 : cur0;
    const int t = threadIdx.x;
    const int CH = (n + 1023) / 1024;
    const int b0 = t * CH;
    int local = 0;
    for (int i = 0; i < CH; ++i) {
        int idx = b0 + i;
        if (idx < n) local += cnt[idx];
    }
    sums[t] = local;
    __syncthreads();
    for (int off = 1; off < 1024; off <<= 1) {
        int x = (t >= off) ? sums[t - off] : 0;
        __syncthreads();
        sums[t] += x;
        __syncthreads();
    }
    int run = sums[t] - local;    // exclusive prefix of this thread's chunk
    for (int i = 0; i < CH; ++i) {
        int idx = b0 + i;
        if (idx < n) {
            rp[idx] = run; cursor[idx] = run;
            run += cnt[idx];
        }
    }
    if (t == 1023) rp[n] = sums[1023];
}

// ---------------------------------------------------------------- batchnorm (both tensors batched)
// STATS layout: [0..N) sum_a, [N..2N) sq_a, [2N..3N) sum_u, [3N..4N) sq_u
__global__ void colstat2_kernel(const __hip_bfloat16* __restrict__ X0,
                                const __hip_bfloat16* __restrict__ X1,
                                float* __restrict__ sums, int M, int N)
{
    __shared__ float ls[256], lq[256];
    const int z = blockIdx.z;
    const __hip_bfloat16* X = z ? X1 : X0;
    float* sm = sums + z * 2 * N;
    int c = blockIdx.x * 64 + (threadIdx.x & 63);
    int rl = threadIdx.x >> 6;
    float s = 0.f, q = 0.f;
    for (int r = blockIdx.y * 4 + rl; r < M; r += gridDim.y * 4) {
        float v = __bfloat162float(X[(size_t)r * N + c]);
        s += v; q = fmaf(v, v, q);
    }
    ls[threadIdx.x] = s; lq[threadIdx.x] = q;
    __syncthreads();
    if (rl == 0) {
        s = ls[threadIdx.x] + ls[threadIdx.x + 64] + ls[threadIdx.x + 128] + ls[threadIdx.x + 192];
        q = lq[threadIdx.x] + lq[threadIdx.x + 64] + lq[threadIdx.x + 128] + lq[threadIdx.x + 192];
        atomicAdd(&sm[c], s);
        atomicAdd(&sm[N + c], q);
    }
}

__global__ void bn2_kernel(__hip_bfloat16* __restrict__ X0, __hip_bfloat16* __restrict__ X1,
                           const float* __restrict__ sums,
                           const float* __restrict__ g, const float* __restrict__ b,
                           int M, int N)
{
    int tid = blockIdx.x * blockDim.x + threadIdx.x;
    if (tid >= 2 * M * N) return;
    const int which = tid >= M * N;
    const int idx = tid - which * M * N;
    const int c = idx % N;
    __hip_bfloat16* X = which ? X1 : X0;
    const float* sm = sums + which * 2 * N;
    float mu = sm[c] / (float)M;
    float var = sm[N + c] / (float)M - mu * mu;
    float x = __bfloat162float(X[idx]);
    X[idx] = __float2bfloat16((x - mu) * rsqrtf(var + 1e-5f) * g[which * N + c]
                              + b[which * N + c]);
}

// ---------------------------------------------------------------- combined output epilogue
__global__ void epilogue_kernel(const float* __restrict__ XA, const float* __restrict__ XU,
                                float* __restrict__ out)
{
    const int row = blockIdx.x;
    const int l = threadIdx.x;   // 64
    if (blockIdx.y == 0) {
        const float* x = XA + (size_t)row * 128;
        float v0 = x[l], v1 = x[l + 64];
        float ss = v0 * v0 + v1 * v1;
        #pragma unroll
        for (int off = 32; off; off >>= 1) ss += __shfl_xor(ss, off);
        float inv = rsqrtf(ss + 1e-12f);
        out[(size_t)row * 128 + l] = v0 * inv;
        out[(size_t)row * 128 + l + 64] = v1 * inv;
    } else {
        const float* x = XU + (size_t)row * 129;
        float* o = out + (size_t)N_NODES * 128;
        float v0 = x[l], v1 = x[l + 64];
        float v2 = (l == 0) ? x[128] : -3.4e38f;
        float m = fmaxf(fmaxf(v0, v1), v2);
        #pragma unroll
        for (int off = 32; off; off >>= 1) m = fmaxf(m, __shfl_xor(m, off));
        float e0 = expf(v0 - m), e1 = expf(v1 - m);
        float e2 = (l == 0) ? expf(v2 - m) : 0.f;
        float s = e0 + e1 + e2;
        #pragma unroll
        for (int off = 32; off; off >>= 1) s += __shfl_xor(s, off);
        float inv = 1.f / s;
        o[(size_t)row * 129 + l] = e0 * inv;
        o[(size_t)row * 129 + l + 64] = e1 * inv;
        if (l == 0) o[(size_t)row * 129 + 128] = e2 * inv;
    }
}

// ---------------------------------------------------------------- host-side plumbing
template<int ACT, typename OUT>
static inline void launch_gemm2(const __hip_bfloat16* A0, const __hip_bfloat16* W0,
                                const float* b0, OUT* C0, int N0,
                                const __hip_bfloat16* A1, const __hip_bfloat16* W1,
                                const float* b1, OUT* C1, int N1,
                                int M, int K, hipStream_t s)
{
    GemmPair P = { A0, A1, W0, W1, b0, b1, (void*)C0, (void*)C1, N0, N1 };
    const int maxN = N0 > N1 ? N0 : N1;
    dim3 grid((maxN + 127) / 128, (M + 127) / 128, 2);
    gemm2_kernel<ACT, OUT><<<grid, 256, 0, s>>>(P, M, K);
}

struct LayerParams {
    const float *kw, *kb, *qw, *qb, *vw, *vb, *arel, *mrel, *prel, *ew, *eb, *alw, *alb;
};

struct CsrRel { const int* rp; const int* src; const float* eav; };

template<int D>
static void run_layer(const LayerParams& P, int fin,
                      const __hip_bfloat16* xa, const __hip_bfloat16* xu,
                      __hip_bfloat16* TA, __hip_bfloat16* TU,
                      __hip_bfloat16* AGA, __hip_bfloat16* AGU,
                      __hip_bfloat16* ya, __hip_bfloat16* yu,
                      const __hip_bfloat16* WQa, const __hip_bfloat16* WQu,
                      const float* Ba, const float* Bu,
                      const __hip_bfloat16* WALa, const __hip_bfloat16* WALu,
                      const CsrRel& au, const CsrRel& ua, hipStream_t s)
{
    const int HD = NH * D;
    const float scale = 1.0f / sqrtf((float)D);

    launch_gemm2<0, __hip_bfloat16>(xa, WQa, Ba, TA, 3 * HD,
                                    xu, WQu, Bu, TU, 3 * HD, N_NODES, fin, s);

    edge_fused_kernel<D><<<2 * N_NODES, 256, 0, s>>>(
        TA, TU, au.rp, au.src, au.eav, ua.rp, ua.src, ua.eav,
        P.prel, P.ew, P.eb, AGA, AGU, scale);

    launch_gemm2<1, __hip_bfloat16>(AGA, WALa, P.alb, ya, HD,
                                    AGU, WALu, P.alb + HD, yu, HD, N_NODES, HD, s);
}

extern "C" void kernel_launch(void* const* d_in, const int* in_sizes, int n_in,
                              void* d_out, int out_size, void* d_ws, size_t ws_size,
                              hipStream_t stream)
{
    // ---- inputs
    const float* x_ant  = (const float*)d_in[0];
    const float* x_user = (const float*)d_in[1];
    const float* ea_au  = (const float*)d_in[2];
    const float* ea_ua  = (const float*)d_in[3];
    LayerParams L1 = {
        (const float*)d_in[4],  (const float*)d_in[5],  (const float*)d_in[6],
        (const float*)d_in[7],  (const float*)d_in[8],  (const float*)d_in[9],
        (const float*)d_in[10], (const float*)d_in[11], (const float*)d_in[12],
        (const float*)d_in[13], (const float*)d_in[14], (const float*)d_in[15],
        (const float*)d_in[16]
    };
    LayerParams L2 = {
        (const float*)d_in[17], (const float*)d_in[18], (const float*)d_in[19],
        (const float*)d_in[20], (const float*)d_in[21], (const float*)d_in[22],
        (const float*)d_in[23], (const float*)d_in[24], (const float*)d_in[25],
        (const float*)d_in[26], (const float*)d_in[27], (const float*)d_in[28],
        (const float*)d_in[29]
    };
    const float* lin1_w  = (const float*)d_in[30];
    const float* lin1_b  = (const float*)d_in[31];
    const float* bn_g    = (const float*)d_in[32];
    const float* bn_b    = (const float*)d_in[33];
    const float* lin2_wa = (const float*)d_in[34];
    const float* lin2_ba = (const float*)d_in[35];
    const float* lin2_wu = (const float*)d_in[36];
    const float* lin2_bu = (const float*)d_in[37];
    const int*   ei_au   = (const int*)d_in[38];
    const int*   ei_ua   = (const int*)d_in[39];

    // ---- workspace arena (byte carve, 256B aligned)
    char* P8 = (char*)d_ws;
    auto carve = [&](size_t bytes) { char* p = P8; P8 += (bytes + 255) & ~(size_t)255; return p; };
    __hip_bfloat16* XA  = (__hip_bfloat16*)carve((size_t)N_NODES * 128 * 2);
    __hip_bfloat16* XU  = (__hip_bfloat16*)carve((size_t)N_NODES * 128 * 2);
    __hip_bfloat16* TA  = (__hip_bfloat16*)carve((size_t)N_NODES * 960 * 2);
    __hip_bfloat16* TU  = (__hip_bfloat16*)carve((size_t)N_NODES * 960 * 2);
    __hip_bfloat16* AGA = (__hip_bfloat16*)carve((size_t)N_NODES * 320 * 2);
    __hip_bfloat16* AGU = (__hip_bfloat16*)carve((size_t)N_NODES * 320 * 2);
    __hip_bfloat16* YA  = (__hip_bfloat16*)carve((size_t)N_NODES * 320 * 2);
    __hip_bfloat16* YU  = (__hip_bfloat16*)carve((size_t)N_NODES * 320 * 2);
    __hip_bfloat16* L1A = (__hip_bfloat16*)carve((size_t)N_NODES * 512 * 2);
    __hip_bfloat16* L1U = (__hip_bfloat16*)carve((size_t)N_NODES * 512 * 2);
    // prepped weights (all built up-front)
    __hip_bfloat16* WQ1A = (__hip_bfloat16*)carve(480 * 128 * 2);
    __hip_bfloat16* WQ1U = (__hip_bfloat16*)carve(480 * 128 * 2);
    __hip_bfloat16* WQ2A = (__hip_bfloat16*)carve(960 * 160 * 2);
    __hip_bfloat16* WQ2U = (__hip_bfloat16*)carve(960 * 160 * 2);
    __hip_bfloat16* WAL1A = (__hip_bfloat16*)carve(160 * 160 * 2);
    __hip_bfloat16* WAL1U = (__hip_bfloat16*)carve(160 * 160 * 2);
    __hip_bfloat16* WAL2A = (__hip_bfloat16*)carve(320 * 320 * 2);
    __hip_bfloat16* WAL2U = (__hip_bfloat16*)carve(320 * 320 * 2);
    __hip_bfloat16* WL1A = (__hip_bfloat16*)carve(512 * 320 * 2);
    __hip_bfloat16* WL1U = (__hip_bfloat16*)carve(512 * 320 * 2);
    __hip_bfloat16* WL2A = (__hip_bfloat16*)carve(128 * 512 * 2);
    __hip_bfloat16* WL2U = (__hip_bfloat16*)carve(129 * 512 * 2);
    float* B1A = (float*)carve(480 * 4);
    float* B1U = (float*)carve(480 * 4);
    float* B2A = (float*)carve(960 * 4);
    float* B2U = (float*)carve(960 * 4);
    float* STATS = (float*)carve(2048 * 4);
    int*   rp_au  = (int*)carve((N_NODES + 1) * 4);
    int*   rp_ua  = (int*)carve((N_NODES + 1) * 4);
    int*   src_au = (int*)carve((size_t)N_EDGES * 4);
    float* eav_au = (float*)carve((size_t)N_EDGES * 4);
    int*   src_ua = (int*)carve((size_t)N_EDGES * 4);
    float* eav_ua = (float*)carve((size_t)N_EDGES * 4);
    int*   cursor = (int*)carve((size_t)2 * N_NODES * 4);
    int*   counts = (int*)carve((size_t)2 * N_NODES * 4);

    const int gE = (N_EDGES + 255) / 256;

    // ---- ALL weight prep up-front (2 launches)
    {
        PrepArgs PA = {
            L1.qw, L1.qb, L1.kw, L1.kb, L1.vw, L1.vb, L1.arel, L1.mrel,
            L2.qw, L2.qb, L2.kw, L2.kb, L2.vw, L2.vb, L2.arel, L2.mrel,
            WQ1A, WQ1U, WQ2A, WQ2U, B1A, B1U, B2A, B2U
        };
        dim3 g((3 * 320 * 161 + 255) / 256, 4);   // max over layers
        prep_qkv4_kernel<<<g, 256, 0, stream>>>(PA);
    }
    {
        TJobs8 J = {{
            { L1.alw,                      WAL1A, 160, 160 },
            { L1.alw + (size_t)160 * 160,  WAL1U, 160, 160 },
            { L2.alw,                      WAL2A, 320, 320 },
            { L2.alw + (size_t)320 * 320,  WAL2U, 320, 320 },
            { lin1_w,                      WL1A,  320, 512 },
            { lin1_w + (size_t)320 * 512,  WL1U,  320, 512 },
            { lin2_wa,                     WL2A,  512, 128 },
            { lin2_wu,                     WL2U,  512, 129 }
        }};
        dim3 g(512 / 32, 512 / 32, 8);
        transpose8_kernel<<<g, 256, 0, stream>>>(J);
    }

    // ---- CSR build (both relations, batched launches)
    hipMemsetAsync(counts, 0, 2 * N_NODES * sizeof(int), stream);
    {
        dim3 g(gE, 2);
        count2_kernel<<<g, 256, 0, stream>>>(ei_au, ei_ua, counts, counts + N_NODES);
    }
    exscan2_kernel<<<2, 1024, 0, stream>>>(counts, rp_au, cursor,
                                           counts + N_NODES, rp_ua, cursor + N_NODES,
                                           N_NODES);
    {
        dim3 g(gE, 2);
        scatter2_kernel<<<g, 256, 0, stream>>>(ei_au, ea_au, ei_ua, ea_ua,
                                               cursor, cursor + N_NODES,
                                               src_au, eav_au, src_ua, eav_ua);
    }
    CsrRel au = { rp_au, src_au, eav_au };
    CsrRel ua = { rp_ua, src_ua, eav_ua };

    // ---- inputs f32 -> bf16 (one launch)
    {
        dim3 g((N_NODES * 128 / 4 + 255) / 256, 2);
        convert_in_kernel<<<g, 256, 0, stream>>>(x_ant, x_user, XA, XU, N_NODES * 128 / 4);
    }

    // ---- HGT layer 1: fin=128, D=16 -> YA/YU [N,160] bf16 (elu applied)
    run_layer<16>(L1, 128, XA, XU, TA, TU, AGA, AGU, YA, YU,
                  WQ1A, WQ1U, B1A, B1U, WAL1A, WAL1U, au, ua, stream);

    // ---- HGT layer 2: fin=160, D=32 -> outputs into TA/TU (table space dead after edge)
    run_layer<32>(L2, 160, YA, YU, TA, TU, AGA, AGU, TA, TU,
                  WQ2A, WQ2U, B2A, B2U, WAL2A, WAL2U, au, ua, stream);

    // ---- lin1 + elu: [N,320] @ [320,512] -> bf16 (paired)
    launch_gemm2<1, __hip_bfloat16>(TA, WL1A, lin1_b, L1A, 512,
                                    TU, WL1U, lin1_b + 512, L1U, 512, N_NODES, 320, stream);

    // ---- batchnorm (population stats), in-place on bf16 (batched)
    hipMemsetAsync(STATS, 0, 2048 * sizeof(float), stream);
    {
        dim3 g(8, 32, 2);
        colstat2_kernel<<<g, 256, 0, stream>>>(L1A, L1U, STATS, N_NODES, 512);
    }
    bn2_kernel<<<(2 * N_NODES * 512 + 255) / 256, 256, 0, stream>>>(
        L1A, L1U, STATS, bn_g, bn_b, N_NODES, 512);

    // ---- lin2 (f32 out, paired) + combined epilogue; OUT buffers reuse AGA/AGU
    float* OUTA = (float*)AGA;   // [N,128] f32
    float* OUTU = (float*)AGU;   // [N,129] f32
    launch_gemm2<0, float>(L1A, WL2A, lin2_ba, OUTA, 128,
                           L1U, WL2U, lin2_bu, OUTU, 129, N_NODES, 512, stream);
    {
        dim3 g(N_NODES, 2);
        epilogue_kernel<<<g, 64, 0, stream>>>(OUTA, OUTU, (float*)d_out);
    }
}

// Round 16
// 861.959 us; speedup vs baseline: 1.1533x; 1.0597x over previous
//
#include <hip/hip_runtime.h>
#include <hip/hip_bf16.h>
#include <math.h>

#define N_NODES 20000
#define N_EDGES 400000
#define NH 10

typedef __attribute__((ext_vector_type(8))) short short8v;
typedef __attribute__((ext_vector_type(4))) float f32x4;

// ---------------------------------------------------------------- helpers
__device__ __forceinline__ float gelu_f(float x) {
    float x3 = x * x * x;
    return 0.5f * x * (1.0f + tanhf(0.7978845608028654f * (x + 0.044715f * x3)));
}
__device__ __forceinline__ float elu_f(float x) {
    return x > 0.0f ? x : (expf(x) - 1.0f);
}
__device__ __forceinline__ float bf_lo(unsigned int w) {
    return __uint_as_float(w << 16);
}
__device__ __forceinline__ float bf_hi(unsigned int w) {
    return __uint_as_float(w & 0xffff0000u);
}
__device__ __forceinline__ unsigned short f2b(float x) {   // RNE f32->bf16 bits
    unsigned int u = __float_as_uint(x);
    return (unsigned short)((u + 0x7fffu + ((u >> 16) & 1u)) >> 16);
}

// ---------------------------------------------------------------- paired MFMA GEMM
// Two independent GEMMs per launch (blockIdx.z). A: AT (f32 converted in staging,
// or bf16; MODE==2 applies BN x*scl+sft during staging). W transposed bf16 [N][K].
// MODE: 0 = plain, 1 = accumulate per-column sum/sumsq of outputs into stats
// (for BN), 2 = BN-normalize A in staging. BM=BN=128, BK=32, register prefetch.
struct GP {
    const void *A0, *A1;
    const __hip_bfloat16 *W0, *W1;
    const float *b0, *b1;
    void *C0, *C1;
    int N0, N1;
    float* stats;            // MODE 1: [z*1024 + {0:sum,512:sq}]
    const float *scl, *sft;  // MODE 2: [z*512 + c]
};
template<int ACT, int MODE, typename AT, typename OUT>
__global__ __launch_bounds__(256) void gemm2_kernel(GP P, int M, int K)
{
    constexpr int PITCH = 40;
    __shared__ __align__(16) unsigned short As[128 * PITCH];
    __shared__ __align__(16) unsigned short Bs[128 * PITCH];
    const int z = blockIdx.z;
    const AT* A  = (const AT*)(z ? P.A1 : P.A0);
    const __hip_bfloat16* WT = z ? P.W1 : P.W0;
    const float* bias = z ? P.b1 : P.b0;
    OUT* C = (OUT*)(z ? P.C1 : P.C0);
    const int N = z ? P.N1 : P.N0;

    const int tid = threadIdx.x;
    const int m0 = blockIdx.y * 128, n0 = blockIdx.x * 128;
    if (n0 >= N) return;
    const int w = tid >> 6, l = tid & 63;
    const int wr = w >> 1, wc = w & 1;
    const int lr = l & 15, lk = l >> 4;

    const int srow = tid >> 1, sseg = (tid & 1) * 16;
    const bool ainb = (m0 + srow) < M;
    const bool binb = (n0 + srow) < N;
    const AT* aptr = A + (size_t)(m0 + srow) * K + sseg;
    const __hip_bfloat16* bptr = WT + (size_t)(n0 + srow) * K + sseg;

    constexpr int NRA = (sizeof(AT) == 4) ? 4 : 2;
    int4 ra[NRA], rb0, rb1;
    auto ld = [&](int k0) {
        #pragma unroll
        for (int i = 0; i < NRA; ++i)
            ra[i] = ainb ? ((const int4*)(aptr + k0))[i] : make_int4(0, 0, 0, 0);
        rb0 = binb ? *(const int4*)(bptr + k0)     : make_int4(0, 0, 0, 0);
        rb1 = binb ? *(const int4*)(bptr + k0 + 8) : make_int4(0, 0, 0, 0);
    };
    auto stage = [&](int k0) {
        if constexpr (sizeof(AT) == 4) {
            const float* fv = (const float*)ra;         // 16 f32
            unsigned int pk[8];
            #pragma unroll
            for (int q = 0; q < 8; ++q)
                pk[q] = (unsigned int)f2b(fv[2 * q]) |
                        ((unsigned int)f2b(fv[2 * q + 1]) << 16);
            *(int4*)&As[srow * PITCH + sseg]     = *(int4*)&pk[0];
            *(int4*)&As[srow * PITCH + sseg + 8] = *(int4*)&pk[4];
        } else if constexpr (MODE == 2) {
            const unsigned int* uv = (const unsigned int*)ra;   // 8 dw = 16 bf16
            const float* scl = P.scl + z * 512;
            const float* sft = P.sft + z * 512;
            unsigned int pk[8];
            #pragma unroll
            for (int q = 0; q < 8; ++q) {
                const int c0 = k0 + sseg + 2 * q;
                float x0 = fmaf(bf_lo(uv[q]), scl[c0], sft[c0]);
                float x1 = fmaf(bf_hi(uv[q]), scl[c0 + 1], sft[c0 + 1]);
                pk[q] = (unsigned int)f2b(x0) | ((unsigned int)f2b(x1) << 16);
            }
            *(int4*)&As[srow * PITCH + sseg]     = *(int4*)&pk[0];
            *(int4*)&As[srow * PITCH + sseg + 8] = *(int4*)&pk[4];
        } else {
            *(int4*)&As[srow * PITCH + sseg]     = ra[0];
            *(int4*)&As[srow * PITCH + sseg + 8] = ra[1];
        }
        *(int4*)&Bs[srow * PITCH + sseg]     = rb0;   // note: B staged by same thread map
        *(int4*)&Bs[srow * PITCH + sseg + 8] = rb1;
    };

    f32x4 acc[4][4] = {};
    ld(0);
    for (int k0 = 0; k0 < K; k0 += 32) {
        // B staging uses same (srow,sseg) map: rb holds 16 bf16 of row srow.
        // (ld loads 16 A-elems and 16 B-elems per thread per tile.)
        stage(k0);
        __syncthreads();
        if (k0 + 32 < K) ld(k0 + 32);
        short8v a[4], b[4];
        #pragma unroll
        for (int mi = 0; mi < 4; ++mi)
            a[mi] = *reinterpret_cast<const short8v*>(
                &As[(wr * 64 + mi * 16 + lr) * PITCH + lk * 8]);
        #pragma unroll
        for (int ni = 0; ni < 4; ++ni)
            b[ni] = *reinterpret_cast<const short8v*>(
                &Bs[(wc * 64 + ni * 16 + lr) * PITCH + lk * 8]);
        #pragma unroll
        for (int mi = 0; mi < 4; ++mi)
            #pragma unroll
            for (int ni = 0; ni < 4; ++ni)
                acc[mi][ni] = __builtin_amdgcn_mfma_f32_16x16x32_bf16(
                    a[mi], b[ni], acc[mi][ni], 0, 0, 0);
        __syncthreads();
    }

    float* cs = (float*)As;   // MODE 1: reuse LDS for column sums (256 f32)
    if constexpr (MODE == 1) {
        if (tid < 256) cs[tid] = 0.f;
        __syncthreads();
    }
    #pragma unroll
    for (int ni = 0; ni < 4; ++ni) {
        const int col = n0 + wc * 64 + ni * 16 + lr;
        if (col >= N) continue;
        const float bv = bias[col];
        float lsum = 0.f, lsq = 0.f;
        #pragma unroll
        for (int mi = 0; mi < 4; ++mi) {
            const int rb = m0 + wr * 64 + mi * 16 + lk * 4;
            #pragma unroll
            for (int j = 0; j < 4; ++j) {
                const int m = rb + j;
                if (m >= M) continue;
                float v = acc[mi][ni][j] + bv;
                if (ACT == 1) v = elu_f(v);
                if constexpr (MODE == 1) { lsum += v; lsq = fmaf(v, v, lsq); }
                if constexpr (sizeof(OUT) == 2)
                    C[(size_t)m * N + col] = __float2bfloat16(v);
                else
                    C[(size_t)m * N + col] = v;
            }
        }
        if constexpr (MODE == 1) {
            const int ct = wc * 64 + ni * 16 + lr;   // 0..127
            atomicAdd(&cs[ct], lsum);
            atomicAdd(&cs[128 + ct], lsq);
        }
    }
    if constexpr (MODE == 1) {
        __syncthreads();
        if (tid < 128) {
            const int col = n0 + tid;
            if (col < N) {
                atomicAdd(&P.stats[z * 1024 + col], cs[tid]);
                atomicAdd(&P.stats[z * 1024 + 512 + col], cs[128 + tid]);
            }
        }
    }
}

// BN scale/shift precompute: x_norm = x*scl + sft
__global__ void bnprep_kernel(const float* __restrict__ S, const float* __restrict__ g,
                              const float* __restrict__ b,
                              float* __restrict__ SCL, float* __restrict__ SFT)
{
    int t = blockIdx.x * 256 + threadIdx.x;
    if (t >= 1024) return;
    const int z = t >> 9, c = t & 511;
    const float mu = S[z * 1024 + c] / (float)N_NODES;
    const float var = S[z * 1024 + 512 + c] / (float)N_NODES - mu * mu;
    const float scl = g[z * 512 + c] * rsqrtf(var + 1e-5f);
    SCL[z * 512 + c] = scl;
    SFT[z * 512 + c] = b[z * 512 + c] - mu * scl;
}

// ---------------------------------------------------------------- batched weight transpose (8 jobs)
struct TJob { const float* in; __hip_bfloat16* out; int K; int N; };
struct TJobs8 { TJob j[8]; };
__global__ void transpose8_kernel(TJobs8 J)
{
    __shared__ float tile[32][33];
    const TJob job = J.j[blockIdx.z];
    const int K = job.K, N = job.N;
    const int nb = blockIdx.x * 32, kb = blockIdx.y * 32;
    if (nb >= N || kb >= K) return;
    const int tx = threadIdx.x & 31, ty = threadIdx.x >> 5;
    for (int j = ty; j < 32; j += 8) {
        int k = kb + j, n = nb + tx;
        tile[j][tx] = (k < K && n < N) ? job.in[(size_t)k * N + n] : 0.f;
    }
    __syncthreads();
    for (int j = ty; j < 32; j += 8) {
        int n = nb + j, k = kb + tx;
        if (n < N && k < K) job.out[(size_t)n * K + k] = __float2bfloat16(tile[tx][j]);
    }
}

// q|k|v weight prep for BOTH layers x BOTH types in one launch (blockIdx.y=0..3).
struct PrepArgs {
    const float *qw1, *qb1, *kw1, *kb1, *vw1, *vb1, *ar1, *mr1;
    const float *qw2, *qb2, *kw2, *kb2, *vw2, *vb2, *ar2, *mr2;
    __hip_bfloat16 *W1a, *W1u, *W2a, *W2u;
    float *B1a, *B1u, *B2a, *B2u;
};
__global__ void prep_qkv4_kernel(PrepArgs A)
{
    const int y = blockIdx.y;
    const int layer = y >> 1, type = y & 1;
    const int D = layer ? 32 : 16;
    const int fin = layer ? 160 : 128;
    const int HD = NH * D;
    const float* qw = layer ? A.qw2 : A.qw1;
    const float* qb = layer ? A.qb2 : A.qb1;
    const float* kw = layer ? A.kw2 : A.kw1;
    const float* kb = layer ? A.kb2 : A.kb1;
    const float* vw = layer ? A.vw2 : A.vw1;
    const float* vb = layer ? A.vb2 : A.vb1;
    const float* ar = layer ? A.ar2 : A.ar1;
    const float* mr = layer ? A.mr2 : A.mr1;
    __hip_bfloat16* WT = layer ? (type ? A.W2u : A.W2a) : (type ? A.W1u : A.W1a);
    float* BIAS = layer ? (type ? A.B2u : A.B2a) : (type ? A.B1u : A.B1a);
    const size_t woff = (size_t)type * fin * HD;
    const size_t roff = (size_t)type * NH * D * D;

    const int F1 = fin + 1;
    int tid = blockIdx.x * blockDim.x + threadIdx.x;
    if (tid >= 3 * HD * F1) return;
    const int f = tid % F1;
    const int col3 = tid / F1;
    const int sec = col3 / HD;
    const int col = col3 - sec * HD;
    float val;
    if (sec == 0) {
        val = (f < fin) ? qw[woff + (size_t)f * HD + col] : qb[type * HD + col];
    } else {
        const float* W = (sec == 1) ? kw : vw;
        const float* B = (sec == 1) ? kb : vb;
        const float* R = ((sec == 1) ? ar : mr) + roff;
        const int h = col / D, e = col - h * D;
        const float* src = (f < fin) ? W + woff + (size_t)f * HD + h * D
                                     : B + type * HD + h * D;
        const float* r = R + (size_t)h * D * D + e;
        float acc = 0.f;
        for (int d = 0; d < D; ++d) acc = fmaf(src[d], r[(size_t)d * D], acc);
        val = acc;
    }
    if (f < fin) WT[(size_t)col3 * fin + f] = __float2bfloat16(val);
    else         BIAS[col3] = val;
}

// ---------------------------------------------------------------- fused edge pipeline (both relations)
// R13 design (measured best: 235us, occ 41%). Block-per-(rel,dst), NO-MAX
// softmax with denominator folded into aggregation.
template<int D>
__global__ __launch_bounds__(256) void edge_fused_kernel(
    const __hip_bfloat16* __restrict__ Ta, const __hip_bfloat16* __restrict__ Tu,
    const int* __restrict__ rp0, const int* __restrict__ src0, const float* __restrict__ eav0,
    const int* __restrict__ rp1, const int* __restrict__ src1, const float* __restrict__ eav1,
    const float* __restrict__ prel, const float* __restrict__ ew,
    const float* __restrict__ eb,                 // [2*NH]
    __hip_bfloat16* __restrict__ outA, __hip_bfloat16* __restrict__ outU,
    float scale)
{
    constexpr int HD = NH * D;
    constexpr int S = 3 * HD;
    constexpr int C = 64;
    constexpr int POS = HD / 8;
    constexpr int G = (POS * 8 <= 256) ? 8 : 4;
    __shared__ float q_s[HD];
    __shared__ float ls[C][NH];
    __shared__ int   srcs[C];
    __shared__ float eas[C];
    __shared__ float prel_s[NH], ew_s[NH], eb_s[NH];

    const int b = blockIdx.x;
    const int rel = b & 1, dst = b >> 1;
    const int t = threadIdx.x;
    const __hip_bfloat16* Tkv = rel ? Tu : Ta;
    const __hip_bfloat16* Tq  = rel ? Ta : Tu;
    const int* rp    = rel ? rp1 : rp0;
    const int* srcA  = rel ? src1 : src0;
    const float* eav = rel ? eav1 : eav0;
    __hip_bfloat16* out = rel ? outA : outU;

    const int s0 = rp[dst], deg = rp[dst + 1] - s0;

    {
        const unsigned int* qrow = (const unsigned int*)(Tq + (size_t)dst * S);
        for (int i = t; i < HD / 2; i += 256) {
            unsigned int wd = qrow[i];
            q_s[2 * i]     = bf_lo(wd);
            q_s[2 * i + 1] = bf_hi(wd);
        }
    }
    if (t < NH) { prel_s[t] = prel[rel * NH + t]; ew_s[t] = ew[rel * NH + t];
                  eb_s[t] = eb[rel * NH + t]; }
    const int apos = t / G, ag = t % G;
    const int ah = (apos * 8) / D;
    float a8[8] = {};
    float ssum = 0.f;
    __syncthreads();

    for (int base = 0; base < deg; base += C) {
        const int cl = min(C, deg - base);
        if (t < cl) {
            srcs[t] = srcA[s0 + base + t];
            eas[t]  = eav[s0 + base + t];
        }
        __syncthreads();
        for (int item = t; item < cl * NH; item += 256) {
            const int p = item / NH, h = item - p * NH;
            const uint4* kr = (const uint4*)(Tkv + (size_t)srcs[p] * S + HD + h * D);
            const float* qh = q_s + h * D;
            float d0 = 0.f;
            #pragma unroll
            for (int c4 = 0; c4 < D / 8; ++c4) {
                const uint4 wd = kr[c4];
                const float* qq = qh + c4 * 8;
                d0 = fmaf(qq[0], bf_lo(wd.x), d0); d0 = fmaf(qq[1], bf_hi(wd.x), d0);
                d0 = fmaf(qq[2], bf_lo(wd.y), d0); d0 = fmaf(qq[3], bf_hi(wd.y), d0);
                d0 = fmaf(qq[4], bf_lo(wd.z), d0); d0 = fmaf(qq[5], bf_hi(wd.z), d0);
                d0 = fmaf(qq[6], bf_lo(wd.w), d0); d0 = fmaf(qq[7], bf_hi(wd.w), d0);
            }
            ls[p][h] = expf(d0 * scale * prel_s[h] + eas[p] * ew_s[h] + eb_s[h]);
        }
        __syncthreads();
        if (apos < POS) {
            for (int p = ag; p < cl; p += G) {
                const uint4* vr = (const uint4*)(Tkv + (size_t)srcs[p] * S + 2 * HD);
                const uint4 wd = vr[apos];
                const float wgt = ls[p][ah];
                ssum += wgt;
                a8[0] = fmaf(wgt, bf_lo(wd.x), a8[0]); a8[1] = fmaf(wgt, bf_hi(wd.x), a8[1]);
                a8[2] = fmaf(wgt, bf_lo(wd.y), a8[2]); a8[3] = fmaf(wgt, bf_hi(wd.y), a8[3]);
                a8[4] = fmaf(wgt, bf_lo(wd.z), a8[4]); a8[5] = fmaf(wgt, bf_hi(wd.z), a8[5]);
                a8[6] = fmaf(wgt, bf_lo(wd.w), a8[6]); a8[7] = fmaf(wgt, bf_hi(wd.w), a8[7]);
            }
        }
        __syncthreads();
    }
    if (apos < POS) {
        #pragma unroll
        for (int off = G / 2; off; off >>= 1) {
            #pragma unroll
            for (int j = 0; j < 8; ++j) a8[j] += __shfl_xor(a8[j], off);
            ssum += __shfl_xor(ssum, off);
        }
        if (ag == 0) {
            const float inv = 1.f / (ssum + 1e-16f);
            uint4 o;
            o.x = (unsigned int)f2b(gelu_f(a8[0] * inv)) |
                  ((unsigned int)f2b(gelu_f(a8[1] * inv)) << 16);
            o.y = (unsigned int)f2b(gelu_f(a8[2] * inv)) |
                  ((unsigned int)f2b(gelu_f(a8[3] * inv)) << 16);
            o.z = (unsigned int)f2b(gelu_f(a8[4] * inv)) |
                  ((unsigned int)f2b(gelu_f(a8[5] * inv)) << 16);
            o.w = (unsigned int)f2b(gelu_f(a8[6] * inv)) |
                  ((unsigned int)f2b(gelu_f(a8[7] * inv)) << 16);
            ((uint4*)(out + (size_t)dst * HD))[apos] = o;
        }
    }
}

// ---------------------------------------------------------------- CSR build (both relations batched)
__global__ void count2_kernel(const int* __restrict__ ei0, const int* __restrict__ ei1,
                              int* __restrict__ cnt0, int* __restrict__ cnt1)
{
    int e = blockIdx.x * blockDim.x + threadIdx.x;
    if (e >= N_EDGES) return;
    if (blockIdx.y == 0) atomicAdd(&cnt0[ei0[N_EDGES + e]], 1);
    else                 atomicAdd(&cnt1[ei1[N_EDGES + e]], 1);
}

__global__ void scatter2_kernel(const int* __restrict__ ei0, const float* __restrict__ ea0,
                                const int* __restrict__ ei1, const float* __restrict__ ea1,
                                int* __restrict__ cur0, int* __restrict__ cur1,
                                int* __restrict__ srcA0, float* __restrict__ eaA0,
                                int* __restrict__ srcA1, float* __restrict__ eaA1)
{
    int e = blockIdx.x * blockDim.x + threadIdx.x;
    if (e >= N_EDGES) return;
    const int y = blockIdx.y;
    const int* ei = y ? ei1 : ei0;
    const float* ea = y ? ea1 : ea0;
    int* cursor = y ? cur1 : cur0;
    int* srcA = y ? srcA1 : srcA0;
    float* eaA = y ? eaA1 : eaA0;
    int dst = ei[N_EDGES + e];
    int pos = atomicAdd(&cursor[dst], 1);
    srcA[pos] = ei[e];
    eaA[pos] = ea[e];
}

__global__ void exscan2_kernel(const int* __restrict__ cnt0, int* __restrict__ rp0, int* __restrict__ cur0,
                               const int* __restrict__ cnt1, int* __restrict__ rp1, int* __restrict__ cur1,
                               int n)
{
    __shared__ int sums[1024];
    const int* cnt = blockIdx.x ? cnt1 : cnt0;
    int* rp = blockIdx.x ? rp1 : rp0;
    int* cursor = blockIdx.x ? cur1 : cur0;
    const int t = threadIdx.x;
    const int CH = (n + 1023) / 1024;
    const int b0 = t * CH;
    int local = 0;
    for (int i = 0; i < CH; ++i) {
        int idx = b0 + i;
        if (idx < n) local += cnt[idx];
    }
    sums[t] = local;
    __syncthreads();
    for (int off = 1; off < 1024; off <<= 1) {
        int x = (t >= off) ? sums[t - off] : 0;
        __syncthreads();
        sums[t] += x;
        __syncthreads();
    }
    int run = sums[t] - local;
    for (int i = 0; i < CH; ++i) {
        int idx = b0 + i;
        if (idx < n) {
            rp[idx] = run; cursor[idx] = run;
            run += cnt[idx];
        }
    }
    if (t == 1023) rp[n] = sums[1023];
}

// ---------------------------------------------------------------- combined output epilogue
__global__ void epilogue_kernel(const float* __restrict__ XA, const float* __restrict__ XU,
                                float* __restrict__ out)
{
    const int row = blockIdx.x;
    const int l = threadIdx.x;   // 64
    if (blockIdx.y == 0) {
        const float* x = XA + (size_t)row * 128;
        float v0 = x[l], v1 = x[l + 64];
        float ss = v0 * v0 + v1 * v1;
        #pragma unroll
        for (int off = 32; off; off >>= 1) ss += __shfl_xor(ss, off);
        float inv = rsqrtf(ss + 1e-12f);
        out[(size_t)row * 128 + l] = v0 * inv;
        out[(size_t)row * 128 + l + 64] = v1 * inv;
    } else {
        const float* x = XU + (size_t)row * 129;
        float* o = out + (size_t)N_NODES * 128;
        float v0 = x[l], v1 = x[l + 64];
        float v2 = (l == 0) ? x[128] : -3.4e38f;
        float m = fmaxf(fmaxf(v0, v1), v2);
        #pragma unroll
        for (int off = 32; off; off >>= 1) m = fmaxf(m, __shfl_xor(m, off));
        float e0 = expf(v0 - m), e1 = expf(v1 - m);
        float e2 = (l == 0) ? expf(v2 - m) : 0.f;
        float s = e0 + e1 + e2;
        #pragma unroll
        for (int off = 32; off; off >>= 1) s += __shfl_xor(s, off);
        float inv = 1.f / s;
        o[(size_t)row * 129 + l] = e0 * inv;
        o[(size_t)row * 129 + l + 64] = e1 * inv;
        if (l == 0) o[(size_t)row * 129 + 128] = e2 * inv;
    }
}

// ---------------------------------------------------------------- host-side plumbing
template<int ACT, int MODE, typename AT, typename OUT>
static inline void launch_gemm2(const AT* A0, const __hip_bfloat16* W0,
                                const float* b0, OUT* C0, int N0,
                                const AT* A1, const __hip_bfloat16* W1,
                                const float* b1, OUT* C1, int N1,
                                int M, int K, hipStream_t s,
                                float* stats = nullptr,
                                const float* scl = nullptr, const float* sft = nullptr)
{
    GP P = { (const void*)A0, (const void*)A1, W0, W1, b0, b1,
             (void*)C0, (void*)C1, N0, N1, stats, scl, sft };
    const int maxN = N0 > N1 ? N0 : N1;
    dim3 grid((maxN + 127) / 128, (M + 127) / 128, 2);
    gemm2_kernel<ACT, MODE, AT, OUT><<<grid, 256, 0, s>>>(P, M, K);
}

struct LayerParams {
    const float *kw, *kb, *qw, *qb, *vw, *vb, *arel, *mrel, *prel, *ew, *eb, *alw, *alb;
};

struct CsrRel { const int* rp; const int* src; const float* eav; };

template<int D, typename AT>
static void run_layer(const LayerParams& P, int fin,
                      const AT* xa, const AT* xu,
                      __hip_bfloat16* TA, __hip_bfloat16* TU,
                      __hip_bfloat16* AGA, __hip_bfloat16* AGU,
                      __hip_bfloat16* ya, __hip_bfloat16* yu,
                      const __hip_bfloat16* WQa, const __hip_bfloat16* WQu,
                      const float* Ba, const float* Bu,
                      const __hip_bfloat16* WALa, const __hip_bfloat16* WALu,
                      const CsrRel& au, const CsrRel& ua, hipStream_t s)
{
    const int HD = NH * D;
    const float scale = 1.0f / sqrtf((float)D);

    launch_gemm2<0, 0, AT, __hip_bfloat16>(xa, WQa, Ba, TA, 3 * HD,
                                           xu, WQu, Bu, TU, 3 * HD, N_NODES, fin, s);

    edge_fused_kernel<D><<<2 * N_NODES, 256, 0, s>>>(
        TA, TU, au.rp, au.src, au.eav, ua.rp, ua.src, ua.eav,
        P.prel, P.ew, P.eb, AGA, AGU, scale);

    launch_gemm2<1, 0, __hip_bfloat16, __hip_bfloat16>(
        AGA, WALa, P.alb, ya, HD, AGU, WALu, P.alb + HD, yu, HD, N_NODES, HD, s);
}

extern "C" void kernel_launch(void* const* d_in, const int* in_sizes, int n_in,
                              void* d_out, int out_size, void* d_ws, size_t ws_size,
                              hipStream_t stream)
{
    // ---- inputs
    const float* x_ant  = (const float*)d_in[0];
    const float* x_user = (const float*)d_in[1];
    const float* ea_au  = (const float*)d_in[2];
    const float* ea_ua  = (const float*)d_in[3];
    LayerParams L1 = {
        (const float*)d_in[4],  (const float*)d_in[5],  (const float*)d_in[6],
        (const float*)d_in[7],  (const float*)d_in[8],  (const float*)d_in[9],
        (const float*)d_in[10], (const float*)d_in[11], (const float*)d_in[12],
        (const float*)d_in[13], (const float*)d_in[14], (const float*)d_in[15],
        (const float*)d_in[16]
    };
    LayerParams L2 = {
        (const float*)d_in[17], (const float*)d_in[18], (const float*)d_in[19],
        (const float*)d_in[20], (const float*)d_in[21], (const float*)d_in[22],
        (const float*)d_in[23], (const float*)d_in[24], (const float*)d_in[25],
        (const float*)d_in[26], (const float*)d_in[27], (const float*)d_in[28],
        (const float*)d_in[29]
    };
    const float* lin1_w  = (const float*)d_in[30];
    const float* lin1_b  = (const float*)d_in[31];
    const float* bn_g    = (const float*)d_in[32];
    const float* bn_b    = (const float*)d_in[33];
    const float* lin2_wa = (const float*)d_in[34];
    const float* lin2_ba = (const float*)d_in[35];
    const float* lin2_wu = (const float*)d_in[36];
    const float* lin2_bu = (const float*)d_in[37];
    const int*   ei_au   = (const int*)d_in[38];
    const int*   ei_ua   = (const int*)d_in[39];

    // ---- workspace arena (byte carve, 256B aligned)
    char* P8 = (char*)d_ws;
    auto carve = [&](size_t bytes) { char* p = P8; P8 += (bytes + 255) & ~(size_t)255; return p; };
    __hip_bfloat16* TA  = (__hip_bfloat16*)carve((size_t)N_NODES * 960 * 2);
    __hip_bfloat16* TU  = (__hip_bfloat16*)carve((size_t)N_NODES * 960 * 2);
    __hip_bfloat16* AGA = (__hip_bfloat16*)carve((size_t)N_NODES * 320 * 2);
    __hip_bfloat16* AGU = (__hip_bfloat16*)carve((size_t)N_NODES * 320 * 2);
    __hip_bfloat16* YA  = (__hip_bfloat16*)carve((size_t)N_NODES * 320 * 2);
    __hip_bfloat16* YU  = (__hip_bfloat16*)carve((size_t)N_NODES * 320 * 2);
    __hip_bfloat16* L1A = (__hip_bfloat16*)carve((size_t)N_NODES * 512 * 2);
    __hip_bfloat16* L1U = (__hip_bfloat16*)carve((size_t)N_NODES * 512 * 2);
    // prepped weights (all built up-front)
    __hip_bfloat16* WQ1A = (__hip_bfloat16*)carve(480 * 128 * 2);
    __hip_bfloat16* WQ1U = (__hip_bfloat16*)carve(480 * 128 * 2);
    __hip_bfloat16* WQ2A = (__hip_bfloat16*)carve(960 * 160 * 2);
    __hip_bfloat16* WQ2U = (__hip_bfloat16*)carve(960 * 160 * 2);
    __hip_bfloat16* WAL1A = (__hip_bfloat16*)carve(160 * 160 * 2);
    __hip_bfloat16* WAL1U = (__hip_bfloat16*)carve(160 * 160 * 2);
    __hip_bfloat16* WAL2A = (__hip_bfloat16*)carve(320 * 320 * 2);
    __hip_bfloat16* WAL2U = (__hip_bfloat16*)carve(320 * 320 * 2);
    __hip_bfloat16* WL1A = (__hip_bfloat16*)carve(512 * 320 * 2);
    __hip_bfloat16* WL1U = (__hip_bfloat16*)carve(512 * 320 * 2);
    __hip_bfloat16* WL2A = (__hip_bfloat16*)carve(128 * 512 * 2);
    __hip_bfloat16* WL2U = (__hip_bfloat16*)carve(129 * 512 * 2);
    float* B1A = (float*)carve(480 * 4);
    float* B1U = (float*)carve(480 * 4);
    float* B2A = (float*)carve(960 * 4);
    float* B2U = (float*)carve(960 * 4);
    float* STATS = (float*)carve(2048 * 4);
    float* SCL = (float*)carve(1024 * 4);
    float* SFT = (float*)carve(1024 * 4);
    int*   rp_au  = (int*)carve((N_NODES + 1) * 4);
    int*   rp_ua  = (int*)carve((N_NODES + 1) * 4);
    int*   src_au = (int*)carve((size_t)N_EDGES * 4);
    float* eav_au = (float*)carve((size_t)N_EDGES * 4);
    int*   src_ua = (int*)carve((size_t)N_EDGES * 4);
    float* eav_ua = (float*)carve((size_t)N_EDGES * 4);
    int*   cursor = (int*)carve((size_t)2 * N_NODES * 4);
    int*   counts = (int*)carve((size_t)2 * N_NODES * 4);

    const int gE = (N_EDGES + 255) / 256;

    // ---- ALL weight prep up-front (2 launches)
    {
        PrepArgs PA = {
            L1.qw, L1.qb, L1.kw, L1.kb, L1.vw, L1.vb, L1.arel, L1.mrel,
            L2.qw, L2.qb, L2.kw, L2.kb, L2.vw, L2.vb, L2.arel, L2.mrel,
            WQ1A, WQ1U, WQ2A, WQ2U, B1A, B1U, B2A, B2U
        };
        dim3 g((3 * 320 * 161 + 255) / 256, 4);
        prep_qkv4_kernel<<<g, 256, 0, stream>>>(PA);
    }
    {
        TJobs8 J = {{
            { L1.alw,                      WAL1A, 160, 160 },
            { L1.alw + (size_t)160 * 160,  WAL1U, 160, 160 },
            { L2.alw,                      WAL2A, 320, 320 },
            { L2.alw + (size_t)320 * 320,  WAL2U, 320, 320 },
            { lin1_w,                      WL1A,  320, 512 },
            { lin1_w + (size_t)320 * 512,  WL1U,  320, 512 },
            { lin2_wa,                     WL2A,  512, 128 },
            { lin2_wu,                     WL2U,  512, 129 }
        }};
        dim3 g(512 / 32, 512 / 32, 8);
        transpose8_kernel<<<g, 256, 0, stream>>>(J);
    }

    // ---- CSR build (both relations, batched launches) + STATS zero
    hipMemsetAsync(counts, 0, 2 * N_NODES * sizeof(int), stream);
    hipMemsetAsync(STATS, 0, 2048 * sizeof(float), stream);
    {
        dim3 g(gE, 2);
        count2_kernel<<<g, 256, 0, stream>>>(ei_au, ei_ua, counts, counts + N_NODES);
    }
    exscan2_kernel<<<2, 1024, 0, stream>>>(counts, rp_au, cursor,
                                           counts + N_NODES, rp_ua, cursor + N_NODES,
                                           N_NODES);
    {
        dim3 g(gE, 2);
        scatter2_kernel<<<g, 256, 0, stream>>>(ei_au, ea_au, ei_ua, ea_ua,
                                               cursor, cursor + N_NODES,
                                               src_au, eav_au, src_ua, eav_ua);
    }
    CsrRel au = { rp_au, src_au, eav_au };
    CsrRel ua = { rp_ua, src_ua, eav_ua };

    // ---- HGT layer 1: fin=128, D=16; A = raw f32 inputs (converted in staging)
    run_layer<16, float>(L1, 128, x_ant, x_user, TA, TU, AGA, AGU, YA, YU,
                         WQ1A, WQ1U, B1A, B1U, WAL1A, WAL1U, au, ua, stream);

    // ---- HGT layer 2: fin=160, D=32 -> outputs into TA/TU
    run_layer<32, __hip_bfloat16>(L2, 160, YA, YU, TA, TU, AGA, AGU, TA, TU,
                                  WQ2A, WQ2U, B2A, B2U, WAL2A, WAL2U, au, ua, stream);

    // ---- lin1 + elu + BN-stats-in-epilogue: [N,320] @ [320,512] -> bf16
    launch_gemm2<1, 1, __hip_bfloat16, __hip_bfloat16>(
        TA, WL1A, lin1_b, L1A, 512, TU, WL1U, lin1_b + 512, L1U, 512,
        N_NODES, 320, stream, STATS);

    // ---- BN scale/shift precompute (tiny)
    bnprep_kernel<<<4, 256, 0, stream>>>(STATS, bn_g, bn_b, SCL, SFT);

    // ---- lin2 with BN applied in A-staging (f32 out, paired) + combined epilogue
    float* OUTA = (float*)AGA;   // [N,128] f32
    float* OUTU = (float*)AGU;   // [N,129] f32
    launch_gemm2<0, 2, __hip_bfloat16, float>(
        L1A, WL2A, lin2_ba, OUTA, 128, L1U, WL2U, lin2_bu, OUTU, 129,
        N_NODES, 512, stream, nullptr, SCL, SFT);
    {
        dim3 g(N_NODES, 2);
        epilogue_kernel<<<g, 64, 0, stream>>>(OUTA, OUTU, (float*)d_out);
    }
}

// Round 17
// 840.631 us; speedup vs baseline: 1.1826x; 1.0254x over previous
//
#include <hip/hip_runtime.h>
#include <hip/hip_bf16.h>
#include <math.h>

#define N_NODES 20000
#define N_EDGES 400000
#define NH 10

typedef __attribute__((ext_vector_type(8))) short short8v;
typedef __attribute__((ext_vector_type(4))) float f32x4;

// ---------------------------------------------------------------- helpers
__device__ __forceinline__ float gelu_f(float x) {
    float x3 = x * x * x;
    return 0.5f * x * (1.0f + tanhf(0.7978845608028654f * (x + 0.044715f * x3)));
}
__device__ __forceinline__ float elu_f(float x) {
    return x > 0.0f ? x : (expf(x) - 1.0f);
}
__device__ __forceinline__ float bf_lo(unsigned int w) {
    return __uint_as_float(w << 16);
}
__device__ __forceinline__ float bf_hi(unsigned int w) {
    return __uint_as_float(w & 0xffff0000u);
}
__device__ __forceinline__ unsigned short f2b(float x) {   // RNE f32->bf16 bits
    unsigned int u = __float_as_uint(x);
    return (unsigned short)((u + 0x7fffu + ((u >> 16) & 1u)) >> 16);
}

// ---------------------------------------------------------------- paired MFMA GEMM
// Two independent GEMMs per launch (blockIdx.z). A: AT (f32 converted in staging,
// or bf16; MODE==2 applies BN x*scl+sft during staging). W transposed bf16 [N][K].
// MODE: 0 = plain, 1 = accumulate per-column sum/sumsq of outputs into stats
// (for BN), 2 = BN-normalize A in staging. BM=BN=128, BK=32, register prefetch.
struct GP {
    const void *A0, *A1;
    const __hip_bfloat16 *W0, *W1;
    const float *b0, *b1;
    void *C0, *C1;
    int N0, N1;
    float* stats;            // MODE 1: [z*1024 + {0:sum,512:sq}]
    const float *scl, *sft;  // MODE 2: [z*512 + c]
};
template<int ACT, int MODE, typename AT, typename OUT>
__global__ __launch_bounds__(256) void gemm2_kernel(GP P, int M, int K)
{
    constexpr int PITCH = 40;
    __shared__ __align__(16) unsigned short As[128 * PITCH];
    __shared__ __align__(16) unsigned short Bs[128 * PITCH];
    const int z = blockIdx.z;
    const AT* A  = (const AT*)(z ? P.A1 : P.A0);
    const __hip_bfloat16* WT = z ? P.W1 : P.W0;
    const float* bias = z ? P.b1 : P.b0;
    OUT* C = (OUT*)(z ? P.C1 : P.C0);
    const int N = z ? P.N1 : P.N0;

    const int tid = threadIdx.x;
    const int m0 = blockIdx.y * 128, n0 = blockIdx.x * 128;
    if (n0 >= N) return;
    const int w = tid >> 6, l = tid & 63;
    const int wr = w >> 1, wc = w & 1;
    const int lr = l & 15, lk = l >> 4;

    const int srow = tid >> 1, sseg = (tid & 1) * 16;
    const bool ainb = (m0 + srow) < M;
    const bool binb = (n0 + srow) < N;
    const AT* aptr = A + (size_t)(m0 + srow) * K + sseg;
    const __hip_bfloat16* bptr = WT + (size_t)(n0 + srow) * K + sseg;

    constexpr int NRA = (sizeof(AT) == 4) ? 4 : 2;
    int4 ra[NRA], rb0, rb1;
    auto ld = [&](int k0) {
        #pragma unroll
        for (int i = 0; i < NRA; ++i)
            ra[i] = ainb ? ((const int4*)(aptr + k0))[i] : make_int4(0, 0, 0, 0);
        rb0 = binb ? *(const int4*)(bptr + k0)     : make_int4(0, 0, 0, 0);
        rb1 = binb ? *(const int4*)(bptr + k0 + 8) : make_int4(0, 0, 0, 0);
    };
    auto stage = [&](int k0) {
        if constexpr (sizeof(AT) == 4) {
            const float* fv = (const float*)ra;
            unsigned int pk[8];
            #pragma unroll
            for (int q = 0; q < 8; ++q)
                pk[q] = (unsigned int)f2b(fv[2 * q]) |
                        ((unsigned int)f2b(fv[2 * q + 1]) << 16);
            *(int4*)&As[srow * PITCH + sseg]     = *(int4*)&pk[0];
            *(int4*)&As[srow * PITCH + sseg + 8] = *(int4*)&pk[4];
        } else if constexpr (MODE == 2) {
            const unsigned int* uv = (const unsigned int*)ra;
            const float* scl = P.scl + z * 512;
            const float* sft = P.sft + z * 512;
            unsigned int pk[8];
            #pragma unroll
            for (int q = 0; q < 8; ++q) {
                const int c0 = k0 + sseg + 2 * q;
                float x0 = fmaf(bf_lo(uv[q]), scl[c0], sft[c0]);
                float x1 = fmaf(bf_hi(uv[q]), scl[c0 + 1], sft[c0 + 1]);
                pk[q] = (unsigned int)f2b(x0) | ((unsigned int)f2b(x1) << 16);
            }
            *(int4*)&As[srow * PITCH + sseg]     = *(int4*)&pk[0];
            *(int4*)&As[srow * PITCH + sseg + 8] = *(int4*)&pk[4];
        } else {
            *(int4*)&As[srow * PITCH + sseg]     = ra[0];
            *(int4*)&As[srow * PITCH + sseg + 8] = ra[1];
        }
        *(int4*)&Bs[srow * PITCH + sseg]     = rb0;
        *(int4*)&Bs[srow * PITCH + sseg + 8] = rb1;
    };

    f32x4 acc[4][4] = {};
    ld(0);
    for (int k0 = 0; k0 < K; k0 += 32) {
        stage(k0);
        __syncthreads();
        if (k0 + 32 < K) ld(k0 + 32);
        short8v a[4], b[4];
        #pragma unroll
        for (int mi = 0; mi < 4; ++mi)
            a[mi] = *reinterpret_cast<const short8v*>(
                &As[(wr * 64 + mi * 16 + lr) * PITCH + lk * 8]);
        #pragma unroll
        for (int ni = 0; ni < 4; ++ni)
            b[ni] = *reinterpret_cast<const short8v*>(
                &Bs[(wc * 64 + ni * 16 + lr) * PITCH + lk * 8]);
        #pragma unroll
        for (int mi = 0; mi < 4; ++mi)
            #pragma unroll
            for (int ni = 0; ni < 4; ++ni)
                acc[mi][ni] = __builtin_amdgcn_mfma_f32_16x16x32_bf16(
                    a[mi], b[ni], acc[mi][ni], 0, 0, 0);
        __syncthreads();
    }

    float* cs = (float*)As;   // MODE 1: reuse LDS for column sums
    if constexpr (MODE == 1) {
        if (tid < 256) cs[tid] = 0.f;
        __syncthreads();
    }
    #pragma unroll
    for (int ni = 0; ni < 4; ++ni) {
        const int col = n0 + wc * 64 + ni * 16 + lr;
        if (col >= N) continue;
        const float bv = bias[col];
        float lsum = 0.f, lsq = 0.f;
        #pragma unroll
        for (int mi = 0; mi < 4; ++mi) {
            const int rb = m0 + wr * 64 + mi * 16 + lk * 4;
            #pragma unroll
            for (int j = 0; j < 4; ++j) {
                const int m = rb + j;
                if (m >= M) continue;
                float v = acc[mi][ni][j] + bv;
                if (ACT == 1) v = elu_f(v);
                if constexpr (MODE == 1) { lsum += v; lsq = fmaf(v, v, lsq); }
                if constexpr (sizeof(OUT) == 2)
                    C[(size_t)m * N + col] = __float2bfloat16(v);
                else
                    C[(size_t)m * N + col] = v;
            }
        }
        if constexpr (MODE == 1) {
            const int ct = wc * 64 + ni * 16 + lr;
            atomicAdd(&cs[ct], lsum);
            atomicAdd(&cs[128 + ct], lsq);
        }
    }
    if constexpr (MODE == 1) {
        __syncthreads();
        if (tid < 128) {
            const int col = n0 + tid;
            if (col < N) {
                atomicAdd(&P.stats[z * 1024 + col], cs[tid]);
                atomicAdd(&P.stats[z * 1024 + 512 + col], cs[128 + tid]);
            }
        }
    }
}

// BN scale/shift precompute: x_norm = x*scl + sft
__global__ void bnprep_kernel(const float* __restrict__ S, const float* __restrict__ g,
                              const float* __restrict__ b,
                              float* __restrict__ SCL, float* __restrict__ SFT)
{
    int t = blockIdx.x * 256 + threadIdx.x;
    if (t >= 1024) return;
    const int z = t >> 9, c = t & 511;
    const float mu = S[z * 1024 + c] / (float)N_NODES;
    const float var = S[z * 1024 + 512 + c] / (float)N_NODES - mu * mu;
    const float scl = g[z * 512 + c] * rsqrtf(var + 1e-5f);
    SCL[z * 512 + c] = scl;
    SFT[z * 512 + c] = b[z * 512 + c] - mu * scl;
}

// ---------------------------------------------------------------- ALL weight prep, ONE launch
// blockIdx.y = 0..3: q|k|v prep (layer = y>>1, type = y&1)
// blockIdx.y = 4..11: weight transpose job (y-4)
struct TJob { const float* in; __hip_bfloat16* out; int K; int N; };
struct PrepAll {
    const float *qw1, *qb1, *kw1, *kb1, *vw1, *vb1, *ar1, *mr1;
    const float *qw2, *qb2, *kw2, *kb2, *vw2, *vb2, *ar2, *mr2;
    __hip_bfloat16 *W1a, *W1u, *W2a, *W2u;
    float *B1a, *B1u, *B2a, *B2u;
    TJob tj[8];
};
__global__ void prep_all_kernel(PrepAll A)
{
    const int y = blockIdx.y;
    if (y >= 4) {
        // ---- transpose job
        __shared__ float tile[32][33];
        const TJob job = A.tj[y - 4];
        const int K = job.K, N = job.N;
        const int nT = (N + 31) / 32;
        const int kb = (blockIdx.x / nT) * 32, nb = (blockIdx.x % nT) * 32;
        if (kb >= K) return;
        const int tx = threadIdx.x & 31, ty = threadIdx.x >> 5;
        for (int j = ty; j < 32; j += 8) {
            int k = kb + j, n = nb + tx;
            tile[j][tx] = (k < K && n < N) ? job.in[(size_t)k * N + n] : 0.f;
        }
        __syncthreads();
        for (int j = ty; j < 32; j += 8) {
            int n = nb + j, k = kb + tx;
            if (n < N && k < K) job.out[(size_t)n * K + k] = __float2bfloat16(tile[tx][j]);
        }
        return;
    }
    // ---- q|k|v prep
    const int layer = y >> 1, type = y & 1;
    const int D = layer ? 32 : 16;
    const int fin = layer ? 160 : 128;
    const int HD = NH * D;
    const float* qw = layer ? A.qw2 : A.qw1;
    const float* qb = layer ? A.qb2 : A.qb1;
    const float* kw = layer ? A.kw2 : A.kw1;
    const float* kb = layer ? A.kb2 : A.kb1;
    const float* vw = layer ? A.vw2 : A.vw1;
    const float* vb = layer ? A.vb2 : A.vb1;
    const float* ar = layer ? A.ar2 : A.ar1;
    const float* mr = layer ? A.mr2 : A.mr1;
    __hip_bfloat16* WT = layer ? (type ? A.W2u : A.W2a) : (type ? A.W1u : A.W1a);
    float* BIAS = layer ? (type ? A.B2u : A.B2a) : (type ? A.B1u : A.B1a);
    const size_t woff = (size_t)type * fin * HD;
    const size_t roff = (size_t)type * NH * D * D;

    const int F1 = fin + 1;
    int tid = blockIdx.x * blockDim.x + threadIdx.x;
    if (tid >= 3 * HD * F1) return;
    const int f = tid % F1;
    const int col3 = tid / F1;
    const int sec = col3 / HD;
    const int col = col3 - sec * HD;
    float val;
    if (sec == 0) {
        val = (f < fin) ? qw[woff + (size_t)f * HD + col] : qb[type * HD + col];
    } else {
        const float* W = (sec == 1) ? kw : vw;
        const float* B = (sec == 1) ? kb : vb;
        const float* R = ((sec == 1) ? ar : mr) + roff;
        const int h = col / D, e = col - h * D;
        const float* src = (f < fin) ? W + woff + (size_t)f * HD + h * D
                                     : B + type * HD + h * D;
        const float* r = R + (size_t)h * D * D + e;
        float acc = 0.f;
        for (int d = 0; d < D; ++d) acc = fmaf(src[d], r[(size_t)d * D], acc);
        val = acc;
    }
    if (f < fin) WT[(size_t)col3 * fin + f] = __float2bfloat16(val);
    else         BIAS[col3] = val;
}

// ---------------------------------------------------------------- fused edge pipeline
// Block-per-dst, BOTH relations processed sequentially per block (grid = N).
// R13 per-relation body (measured best); NO-MAX softmax, denominator folded
// into aggregation. Halved block count amortizes per-block dispatch overhead.
template<int D>
__global__ __launch_bounds__(256) void edge_fused_kernel(
    const __hip_bfloat16* __restrict__ Ta, const __hip_bfloat16* __restrict__ Tu,
    const int* __restrict__ rp0, const int* __restrict__ src0, const float* __restrict__ eav0,
    const int* __restrict__ rp1, const int* __restrict__ src1, const float* __restrict__ eav1,
    const float* __restrict__ prel, const float* __restrict__ ew,
    const float* __restrict__ eb,                 // [2*NH]
    __hip_bfloat16* __restrict__ outA, __hip_bfloat16* __restrict__ outU,
    float scale)
{
    constexpr int HD = NH * D;
    constexpr int S = 3 * HD;
    constexpr int C = 64;
    constexpr int POS = HD / 8;
    constexpr int G = (POS * 8 <= 256) ? 8 : 4;
    __shared__ float q_s[HD];
    __shared__ float ls[C][NH];
    __shared__ int   srcs[C];
    __shared__ float eas[C];
    __shared__ float prel_s[2 * NH], ew_s[2 * NH], eb_s[2 * NH];

    const int dst = blockIdx.x;
    const int t = threadIdx.x;
    if (t < 2 * NH) { prel_s[t] = prel[t]; ew_s[t] = ew[t]; eb_s[t] = eb[t]; }
    const int apos = t / G, ag = t % G;
    const int ah = (apos * 8) / D;

    for (int rel = 0; rel < 2; ++rel) {
        const __hip_bfloat16* Tkv = rel ? Tu : Ta;
        const __hip_bfloat16* Tq  = rel ? Ta : Tu;
        const int* rp    = rel ? rp1 : rp0;
        const int* srcA  = rel ? src1 : src0;
        const float* eav = rel ? eav1 : eav0;
        __hip_bfloat16* out = rel ? outA : outU;
        const int s0 = rp[dst], deg = rp[dst + 1] - s0;

        // stage q row (bf16 -> f32); prior iteration finished all LDS reads
        // before its last barrier, so overwrite is safe.
        {
            const unsigned int* qrow = (const unsigned int*)(Tq + (size_t)dst * S);
            for (int i = t; i < HD / 2; i += 256) {
                unsigned int wd = qrow[i];
                q_s[2 * i]     = bf_lo(wd);
                q_s[2 * i + 1] = bf_hi(wd);
            }
        }
        float a8[8] = {};
        float ssum = 0.f;
        __syncthreads();

        for (int base = 0; base < deg; base += C) {
            const int cl = min(C, deg - base);
            if (t < cl) {
                srcs[t] = srcA[s0 + base + t];
                eas[t]  = eav[s0 + base + t];
            }
            __syncthreads();
            for (int item = t; item < cl * NH; item += 256) {
                const int p = item / NH, h = item - p * NH;
                const uint4* kr = (const uint4*)(Tkv + (size_t)srcs[p] * S + HD + h * D);
                const float* qh = q_s + h * D;
                float d0 = 0.f;
                #pragma unroll
                for (int c4 = 0; c4 < D / 8; ++c4) {
                    const uint4 wd = kr[c4];
                    const float* qq = qh + c4 * 8;
                    d0 = fmaf(qq[0], bf_lo(wd.x), d0); d0 = fmaf(qq[1], bf_hi(wd.x), d0);
                    d0 = fmaf(qq[2], bf_lo(wd.y), d0); d0 = fmaf(qq[3], bf_hi(wd.y), d0);
                    d0 = fmaf(qq[4], bf_lo(wd.z), d0); d0 = fmaf(qq[5], bf_hi(wd.z), d0);
                    d0 = fmaf(qq[6], bf_lo(wd.w), d0); d0 = fmaf(qq[7], bf_hi(wd.w), d0);
                }
                ls[p][h] = expf(d0 * scale * prel_s[rel * NH + h]
                                + eas[p] * ew_s[rel * NH + h] + eb_s[rel * NH + h]);
            }
            __syncthreads();
            if (apos < POS) {
                for (int p = ag; p < cl; p += G) {
                    const uint4* vr = (const uint4*)(Tkv + (size_t)srcs[p] * S + 2 * HD);
                    const uint4 wd = vr[apos];
                    const float wgt = ls[p][ah];
                    ssum += wgt;
                    a8[0] = fmaf(wgt, bf_lo(wd.x), a8[0]); a8[1] = fmaf(wgt, bf_hi(wd.x), a8[1]);
                    a8[2] = fmaf(wgt, bf_lo(wd.y), a8[2]); a8[3] = fmaf(wgt, bf_hi(wd.y), a8[3]);
                    a8[4] = fmaf(wgt, bf_lo(wd.z), a8[4]); a8[5] = fmaf(wgt, bf_hi(wd.z), a8[5]);
                    a8[6] = fmaf(wgt, bf_lo(wd.w), a8[6]); a8[7] = fmaf(wgt, bf_hi(wd.w), a8[7]);
                }
            }
            __syncthreads();
        }
        if (apos < POS) {
            #pragma unroll
            for (int off = G / 2; off; off >>= 1) {
                #pragma unroll
                for (int j = 0; j < 8; ++j) a8[j] += __shfl_xor(a8[j], off);
                ssum += __shfl_xor(ssum, off);
            }
            if (ag == 0) {
                const float inv = 1.f / (ssum + 1e-16f);
                uint4 o;
                o.x = (unsigned int)f2b(gelu_f(a8[0] * inv)) |
                      ((unsigned int)f2b(gelu_f(a8[1] * inv)) << 16);
                o.y = (unsigned int)f2b(gelu_f(a8[2] * inv)) |
                      ((unsigned int)f2b(gelu_f(a8[3] * inv)) << 16);
                o.z = (unsigned int)f2b(gelu_f(a8[4] * inv)) |
                      ((unsigned int)f2b(gelu_f(a8[5] * inv)) << 16);
                o.w = (unsigned int)f2b(gelu_f(a8[6] * inv)) |
                      ((unsigned int)f2b(gelu_f(a8[7] * inv)) << 16);
                ((uint4*)(out + (size_t)dst * HD))[apos] = o;
            }
        }
        __syncthreads();   // protect q_s/srcs re-staging in next rel pass
    }
}

// ---------------------------------------------------------------- CSR build (both relations batched)
__global__ void count2_kernel(const int* __restrict__ ei0, const int* __restrict__ ei1,
                              int* __restrict__ cnt0, int* __restrict__ cnt1)
{
    int e = blockIdx.x * blockDim.x + threadIdx.x;
    if (e >= N_EDGES) return;
    if (blockIdx.y == 0) atomicAdd(&cnt0[ei0[N_EDGES + e]], 1);
    else                 atomicAdd(&cnt1[ei1[N_EDGES + e]], 1);
}

__global__ void scatter2_kernel(const int* __restrict__ ei0, const float* __restrict__ ea0,
                                const int* __restrict__ ei1, const float* __restrict__ ea1,
                                int* __restrict__ cur0, int* __restrict__ cur1,
                                int* __restrict__ srcA0, float* __restrict__ eaA0,
                                int* __restrict__ srcA1, float* __restrict__ eaA1)
{
    int e = blockIdx.x * blockDim.x + threadIdx.x;
    if (e >= N_EDGES) return;
    const int y = blockIdx.y;
    const int* ei = y ? ei1 : ei0;
    const float* ea = y ? ea1 : ea0;
    int* cursor = y ? cur1 : cur0;
    int* srcA = y ? srcA1 : srcA0;
    float* eaA = y ? eaA1 : eaA0;
    int dst = ei[N_EDGES + e];
    int pos = atomicAdd(&cursor[dst], 1);
    srcA[pos] = ei[e];
    eaA[pos] = ea[e];
}

__global__ void exscan2_kernel(const int* __restrict__ cnt0, int* __restrict__ rp0, int* __restrict__ cur0,
                               const int* __restrict__ cnt1, int* __restrict__ rp1, int* __restrict__ cur1,
                               int n)
{
    __shared__ int sums[1024];
    const int* cnt = blockIdx.x ? cnt1 : cnt0;
    int* rp = blockIdx.x ? rp1 : rp0;
    int* cursor = blockIdx.x ? cur1 : cur0;
    const int t = threadIdx.x;
    const int CH = (n + 1023) / 1024;
    const int b0 = t * CH;
    int local = 0;
    for (int i = 0; i < CH; ++i) {
        int idx = b0 + i;
        if (idx < n) local += cnt[idx];
    }
    sums[t] = local;
    __syncthreads();
    for (int off = 1; off < 1024; off <<= 1) {
        int x = (t >= off) ? sums[t - off] : 0;
        __syncthreads();
        sums[t] += x;
        __syncthreads();
    }
    int run = sums[t] - local;
    for (int i = 0; i < CH; ++i) {
        int idx = b0 + i;
        if (idx < n) {
            rp[idx] = run; cursor[idx] = run;
            run += cnt[idx];
        }
    }
    if (t == 1023) rp[n] = sums[1023];
}

// ---------------------------------------------------------------- combined output epilogue
__global__ void epilogue_kernel(const float* __restrict__ XA, const float* __restrict__ XU,
                                float* __restrict__ out)
{
    const int row = blockIdx.x;
    const int l = threadIdx.x;   // 64
    if (blockIdx.y == 0) {
        const float* x = XA + (size_t)row * 128;
        float v0 = x[l], v1 = x[l + 64];
        float ss = v0 * v0 + v1 * v1;
        #pragma unroll
        for (int off = 32; off; off >>= 1) ss += __shfl_xor(ss, off);
        float inv = rsqrtf(ss + 1e-12f);
        out[(size_t)row * 128 + l] = v0 * inv;
        out[(size_t)row * 128 + l + 64] = v1 * inv;
    } else {
        const float* x = XU + (size_t)row * 129;
        float* o = out + (size_t)N_NODES * 128;
        float v0 = x[l], v1 = x[l + 64];
        float v2 = (l == 0) ? x[128] : -3.4e38f;
        float m = fmaxf(fmaxf(v0, v1), v2);
        #pragma unroll
        for (int off = 32; off; off >>= 1) m = fmaxf(m, __shfl_xor(m, off));
        float e0 = expf(v0 - m), e1 = expf(v1 - m);
        float e2 = (l == 0) ? expf(v2 - m) : 0.f;
        float s = e0 + e1 + e2;
        #pragma unroll
        for (int off = 32; off; off >>= 1) s += __shfl_xor(s, off);
        float inv = 1.f / s;
        o[(size_t)row * 129 + l] = e0 * inv;
        o[(size_t)row * 129 + l + 64] = e1 * inv;
        if (l == 0) o[(size_t)row * 129 + 128] = e2 * inv;
    }
}

// ---------------------------------------------------------------- host-side plumbing
template<int ACT, int MODE, typename AT, typename OUT>
static inline void launch_gemm2(const AT* A0, const __hip_bfloat16* W0,
                                const float* b0, OUT* C0, int N0,
                                const AT* A1, const __hip_bfloat16* W1,
                                const float* b1, OUT* C1, int N1,
                                int M, int K, hipStream_t s,
                                float* stats = nullptr,
                                const float* scl = nullptr, const float* sft = nullptr)
{
    GP P = { (const void*)A0, (const void*)A1, W0, W1, b0, b1,
             (void*)C0, (void*)C1, N0, N1, stats, scl, sft };
    const int maxN = N0 > N1 ? N0 : N1;
    dim3 grid((maxN + 127) / 128, (M + 127) / 128, 2);
    gemm2_kernel<ACT, MODE, AT, OUT><<<grid, 256, 0, s>>>(P, M, K);
}

struct LayerParams {
    const float *kw, *kb, *qw, *qb, *vw, *vb, *arel, *mrel, *prel, *ew, *eb, *alw, *alb;
};

struct CsrRel { const int* rp; const int* src; const float* eav; };

template<int D, typename AT>
static void run_layer(const LayerParams& P, int fin,
                      const AT* xa, const AT* xu,
                      __hip_bfloat16* TA, __hip_bfloat16* TU,
                      __hip_bfloat16* AGA, __hip_bfloat16* AGU,
                      __hip_bfloat16* ya, __hip_bfloat16* yu,
                      const __hip_bfloat16* WQa, const __hip_bfloat16* WQu,
                      const float* Ba, const float* Bu,
                      const __hip_bfloat16* WALa, const __hip_bfloat16* WALu,
                      const CsrRel& au, const CsrRel& ua, hipStream_t s)
{
    const int HD = NH * D;
    const float scale = 1.0f / sqrtf((float)D);

    launch_gemm2<0, 0, AT, __hip_bfloat16>(xa, WQa, Ba, TA, 3 * HD,
                                           xu, WQu, Bu, TU, 3 * HD, N_NODES, fin, s);

    edge_fused_kernel<D><<<N_NODES, 256, 0, s>>>(
        TA, TU, au.rp, au.src, au.eav, ua.rp, ua.src, ua.eav,
        P.prel, P.ew, P.eb, AGA, AGU, scale);

    launch_gemm2<1, 0, __hip_bfloat16, __hip_bfloat16>(
        AGA, WALa, P.alb, ya, HD, AGU, WALu, P.alb + HD, yu, HD, N_NODES, HD, s);
}

extern "C" void kernel_launch(void* const* d_in, const int* in_sizes, int n_in,
                              void* d_out, int out_size, void* d_ws, size_t ws_size,
                              hipStream_t stream)
{
    // ---- inputs
    const float* x_ant  = (const float*)d_in[0];
    const float* x_user = (const float*)d_in[1];
    const float* ea_au  = (const float*)d_in[2];
    const float* ea_ua  = (const float*)d_in[3];
    LayerParams L1 = {
        (const float*)d_in[4],  (const float*)d_in[5],  (const float*)d_in[6],
        (const float*)d_in[7],  (const float*)d_in[8],  (const float*)d_in[9],
        (const float*)d_in[10], (const float*)d_in[11], (const float*)d_in[12],
        (const float*)d_in[13], (const float*)d_in[14], (const float*)d_in[15],
        (const float*)d_in[16]
    };
    LayerParams L2 = {
        (const float*)d_in[17], (const float*)d_in[18], (const float*)d_in[19],
        (const float*)d_in[20], (const float*)d_in[21], (const float*)d_in[22],
        (const float*)d_in[23], (const float*)d_in[24], (const float*)d_in[25],
        (const float*)d_in[26], (const float*)d_in[27], (const float*)d_in[28],
        (const float*)d_in[29]
    };
    const float* lin1_w  = (const float*)d_in[30];
    const float* lin1_b  = (const float*)d_in[31];
    const float* bn_g    = (const float*)d_in[32];
    const float* bn_b    = (const float*)d_in[33];
    const float* lin2_wa = (const float*)d_in[34];
    const float* lin2_ba = (const float*)d_in[35];
    const float* lin2_wu = (const float*)d_in[36];
    const float* lin2_bu = (const float*)d_in[37];
    const int*   ei_au   = (const int*)d_in[38];
    const int*   ei_ua   = (const int*)d_in[39];

    // ---- workspace arena (byte carve, 256B aligned)
    char* P8 = (char*)d_ws;
    auto carve = [&](size_t bytes) { char* p = P8; P8 += (bytes + 255) & ~(size_t)255; return p; };
    __hip_bfloat16* TA  = (__hip_bfloat16*)carve((size_t)N_NODES * 960 * 2);
    __hip_bfloat16* TU  = (__hip_bfloat16*)carve((size_t)N_NODES * 960 * 2);
    __hip_bfloat16* AGA = (__hip_bfloat16*)carve((size_t)N_NODES * 320 * 2);
    __hip_bfloat16* AGU = (__hip_bfloat16*)carve((size_t)N_NODES * 320 * 2);
    __hip_bfloat16* YA  = (__hip_bfloat16*)carve((size_t)N_NODES * 320 * 2);
    __hip_bfloat16* YU  = (__hip_bfloat16*)carve((size_t)N_NODES * 320 * 2);
    __hip_bfloat16* L1A = (__hip_bfloat16*)carve((size_t)N_NODES * 512 * 2);
    __hip_bfloat16* L1U = (__hip_bfloat16*)carve((size_t)N_NODES * 512 * 2);
    __hip_bfloat16* WQ1A = (__hip_bfloat16*)carve(480 * 128 * 2);
    __hip_bfloat16* WQ1U = (__hip_bfloat16*)carve(480 * 128 * 2);
    __hip_bfloat16* WQ2A = (__hip_bfloat16*)carve(960 * 160 * 2);
    __hip_bfloat16* WQ2U = (__hip_bfloat16*)carve(960 * 160 * 2);
    __hip_bfloat16* WAL1A = (__hip_bfloat16*)carve(160 * 160 * 2);
    __hip_bfloat16* WAL1U = (__hip_bfloat16*)carve(160 * 160 * 2);
    __hip_bfloat16* WAL2A = (__hip_bfloat16*)carve(320 * 320 * 2);
    __hip_bfloat16* WAL2U = (__hip_bfloat16*)carve(320 * 320 * 2);
    __hip_bfloat16* WL1A = (__hip_bfloat16*)carve(512 * 320 * 2);
    __hip_bfloat16* WL1U = (__hip_bfloat16*)carve(512 * 320 * 2);
    __hip_bfloat16* WL2A = (__hip_bfloat16*)carve(128 * 512 * 2);
    __hip_bfloat16* WL2U = (__hip_bfloat16*)carve(129 * 512 * 2);
    float* B1A = (float*)carve(480 * 4);
    float* B1U = (float*)carve(480 * 4);
    float* B2A = (float*)carve(960 * 4);
    float* B2U = (float*)carve(960 * 4);
    float* SCL = (float*)carve(1024 * 4);
    float* SFT = (float*)carve(1024 * 4);
    int*   rp_au  = (int*)carve((N_NODES + 1) * 4);
    int*   rp_ua  = (int*)carve((N_NODES + 1) * 4);
    int*   src_au = (int*)carve((size_t)N_EDGES * 4);
    float* eav_au = (float*)carve((size_t)N_EDGES * 4);
    int*   src_ua = (int*)carve((size_t)N_EDGES * 4);
    float* eav_ua = (float*)carve((size_t)N_EDGES * 4);
    int*   cursor = (int*)carve((size_t)2 * N_NODES * 4);
    // counts + STATS carved contiguously -> single memset
    int*   counts = (int*)carve((size_t)2 * N_NODES * 4);   // 160000B (256-mult)
    float* STATS  = (float*)carve(2048 * 4);

    const int gE = (N_EDGES + 255) / 256;

    // ---- ALL weight prep in ONE launch
    {
        PrepAll PA = {
            L1.qw, L1.qb, L1.kw, L1.kb, L1.vw, L1.vb, L1.arel, L1.mrel,
            L2.qw, L2.qb, L2.kw, L2.kb, L2.vw, L2.vb, L2.arel, L2.mrel,
            WQ1A, WQ1U, WQ2A, WQ2U, B1A, B1U, B2A, B2U,
            {{ L1.alw,                      WAL1A, 160, 160 },
             { L1.alw + (size_t)160 * 160,  WAL1U, 160, 160 },
             { L2.alw,                      WAL2A, 320, 320 },
             { L2.alw + (size_t)320 * 320,  WAL2U, 320, 320 },
             { lin1_w,                      WL1A,  320, 512 },
             { lin1_w + (size_t)320 * 512,  WL1U,  320, 512 },
             { lin2_wa,                     WL2A,  512, 128 },
             { lin2_wu,                     WL2U,  512, 129 }}
        };
        dim3 g((3 * 320 * 161 + 255) / 256, 12);   // 605 x-blocks covers all jobs
        prep_all_kernel<<<g, 256, 0, stream>>>(PA);
    }

    // ---- CSR build + STATS zero (counts/STATS contiguous -> one memset)
    hipMemsetAsync(counts, 0, 2 * N_NODES * sizeof(int) + 2048 * sizeof(float), stream);
    {
        dim3 g(gE, 2);
        count2_kernel<<<g, 256, 0, stream>>>(ei_au, ei_ua, counts, counts + N_NODES);
    }
    exscan2_kernel<<<2, 1024, 0, stream>>>(counts, rp_au, cursor,
                                           counts + N_NODES, rp_ua, cursor + N_NODES,
                                           N_NODES);
    {
        dim3 g(gE, 2);
        scatter2_kernel<<<g, 256, 0, stream>>>(ei_au, ea_au, ei_ua, ea_ua,
                                               cursor, cursor + N_NODES,
                                               src_au, eav_au, src_ua, eav_ua);
    }
    CsrRel au = { rp_au, src_au, eav_au };
    CsrRel ua = { rp_ua, src_ua, eav_ua };

    // ---- HGT layer 1: fin=128, D=16; A = raw f32 inputs (converted in staging)
    run_layer<16, float>(L1, 128, x_ant, x_user, TA, TU, AGA, AGU, YA, YU,
                         WQ1A, WQ1U, B1A, B1U, WAL1A, WAL1U, au, ua, stream);

    // ---- HGT layer 2: fin=160, D=32 -> outputs into TA/TU
    run_layer<32, __hip_bfloat16>(L2, 160, YA, YU, TA, TU, AGA, AGU, TA, TU,
                                  WQ2A, WQ2U, B2A, B2U, WAL2A, WAL2U, au, ua, stream);

    // ---- lin1 + elu + BN-stats-in-epilogue: [N,320] @ [320,512] -> bf16
    launch_gemm2<1, 1, __hip_bfloat16, __hip_bfloat16>(
        TA, WL1A, lin1_b, L1A, 512, TU, WL1U, lin1_b + 512, L1U, 512,
        N_NODES, 320, stream, STATS);

    // ---- BN scale/shift precompute (tiny)
    bnprep_kernel<<<4, 256, 0, stream>>>(STATS, bn_g, bn_b, SCL, SFT);

    // ---- lin2 with BN applied in A-staging (f32 out, paired) + combined epilogue
    float* OUTA = (float*)AGA;   // [N,128] f32
    float* OUTU = (float*)AGU;   // [N,129] f32
    launch_gemm2<0, 2, __hip_bfloat16, float>(
        L1A, WL2A, lin2_ba, OUTA, 128, L1U, WL2U, lin2_bu, OUTU, 129,
        N_NODES, 512, stream, nullptr, SCL, SFT);
    {
        dim3 g(N_NODES, 2);
        epilogue_kernel<<<g, 64, 0, stream>>>(OUTA, OUTU, (float*)d_out);
    }
}